// Round 5
// baseline (3456.322 us; speedup 1.0000x reference)
//
#include <hip/hip_runtime.h>
#include <hip/hip_bf16.h>

// SpikingLayer: T=64 sequential LIF steps, cur = W @ f, W ~12% dense.
// Round-5 structure:
//   1. build_csr: single coalesced pass over W -> CSR (f32 val + u16 col),
//      rows padded to 4 entries, segments claimed via atomicAdd (layout order
//      nondeterministic, per-row content/order fixed -> output deterministic).
//   2. persist_phaser: ONE persistent kernel, 1024 blocks x 512 threads
//      (__launch_bounds__(512,8) => 4 blocks/CU, 32 waves/CU, all co-resident
//      per the k x 256 capacity rule). Wave per row. Cross-block sync via a
//      step-indexed hierarchical phaser (32 groups x 32 blocks on distinct
//      cache lines -> 1 global word per step) -- no same-address serialization,
//      no counter resets (replay-safe). Firing state = 8192-bit mask,
//      double-buffered u32-word-per-block.
// Output layout (flat): fires[T][N] at 0, vs[T][N] at T*N.

#define N_NEURONS 8192
#define T_STEPS   64
#define DECAY     0.9f
#define THRESH    1.0f
#define NNZ_CAP   9437184u  // 14.06% density cap; actual ~12.3% + <=3/row pad
#define STAGE_CAP 1536      // max nnz/row ~1175 (mean 1030) + pad

#define PS_NBLOCKS 1024
#define PS_THREADS 512
#define PS_GROUPS  32       // 32 blocks per group

// ws byte layout:
#define WS_V_OFF    0         // 8192 f32  (dense fallback)
#define WS_FB0_OFF  32768     // 8192 f32  (dense fallback)
#define WS_FB1_OFF  65536     // 8192 f32  (dense fallback)
#define WS_MW_OFF   98304     // u32 mw[2][1024] firing-mask words
#define WS_GCNT_OFF 106496    // u32 gcnt[32][64] group arrival counters
#define WS_GARR_OFF 114688    // u32 garr[64] group-closer counters
#define WS_RS_OFF   114944    // 8192 u32 row_start
#define WS_RE_OFF   147712    // 8192 u32 row_end
#define WS_CNT_OFF  180480    // u32 nnz counter
#define WS_VAL_OFF  180608    // NNZ_CAP f32 (16B aligned)
#define WS_COL_OFF  (WS_VAL_OFF + (size_t)NNZ_CAP * 4)
#define WS_REQUIRED (WS_COL_OFF + (size_t)NNZ_CAP * 2)

__global__ __launch_bounds__(256) void init_state(const float* __restrict__ f0,
                                                  const float* __restrict__ v0,
                                                  float* __restrict__ v,
                                                  float* __restrict__ fbuf0,
                                                  unsigned* __restrict__ mw,
                                                  unsigned* __restrict__ gcnt,
                                                  unsigned* __restrict__ garr,
                                                  unsigned* __restrict__ counter) {
    int i = blockIdx.x * 256 + threadIdx.x;
    if (i < N_NEURONS) {
        v[i] = v0[i];
        fbuf0[i] = f0[i];
    }
    if (i < PS_NBLOCKS) {  // initial mask word for block i (8 rows -> 8 bits)
        unsigned b = 0;
        #pragma unroll
        for (int j = 0; j < 8; ++j) b |= (f0[i * 8 + j] != 0.f ? 1u : 0u) << j;
        mw[i] = b;  // mw[0][i]
    }
    if (i < PS_GROUPS * T_STEPS) gcnt[i] = 0u;
    if (i < T_STEPS) garr[i] = 0u;
    if (i == 0) *counter = 0u;
}

// Single-pass CSR build: coalesced float4 read, ballot-compaction into LDS
// (column order preserved), atomicAdd to claim the (4-padded) segment, then
// coalesced dump. One 256 MB read of W total.
__global__ __launch_bounds__(256) void build_csr(const float* __restrict__ W,
                                                 unsigned* __restrict__ row_start,
                                                 unsigned* __restrict__ row_end,
                                                 float* __restrict__ val,
                                                 unsigned short* __restrict__ col,
                                                 unsigned* __restrict__ counter) {
    __shared__ float          sval[4][STAGE_CAP];
    __shared__ unsigned short scol[4][STAGE_CAP];

    const int wave = threadIdx.x >> 6, lane = threadIdx.x & 63;
    const int row = blockIdx.x * 4 + wave;
    const float4* Wr = (const float4*)(W + (size_t)row * N_NEURONS);
    const unsigned long long lt = ((unsigned long long)1 << lane) - 1;

    unsigned cnt = 0;  // wave-uniform running nnz
    for (int k = 0; k < 32; ++k) {
        const int idx = k * 64 + lane;
        float4 w = Wr[idx];
        const int c0 = idx * 4;
        unsigned long long m;
        m = __ballot(w.x != 0.f);
        if (w.x != 0.f) { unsigned p = cnt + (unsigned)__popcll(m & lt); sval[wave][p] = w.x; scol[wave][p] = (unsigned short)c0; }
        cnt += (unsigned)__popcll(m);
        m = __ballot(w.y != 0.f);
        if (w.y != 0.f) { unsigned p = cnt + (unsigned)__popcll(m & lt); sval[wave][p] = w.y; scol[wave][p] = (unsigned short)(c0 + 1); }
        cnt += (unsigned)__popcll(m);
        m = __ballot(w.z != 0.f);
        if (w.z != 0.f) { unsigned p = cnt + (unsigned)__popcll(m & lt); sval[wave][p] = w.z; scol[wave][p] = (unsigned short)(c0 + 2); }
        cnt += (unsigned)__popcll(m);
        m = __ballot(w.w != 0.f);
        if (w.w != 0.f) { unsigned p = cnt + (unsigned)__popcll(m & lt); sval[wave][p] = w.w; scol[wave][p] = (unsigned short)(c0 + 3); }
        cnt += (unsigned)__popcll(m);
    }

    const unsigned padded = (cnt + 3u) & ~3u;  // float4/uint2 alignment in step
    if (lane < (int)(padded - cnt)) { sval[wave][cnt + lane] = 0.f; scol[wave][cnt + lane] = 0; }

    unsigned gbase = 0;
    if (lane == 0) gbase = atomicAdd(counter, padded);
    gbase = (unsigned)__shfl((int)gbase, 0);
    if (lane == 0) { row_start[row] = gbase; row_end[row] = gbase + padded; }
    __syncthreads();

    for (unsigned i = lane; i < padded; i += 64) {
        val[gbase + i] = sval[wave][i];
        col[gbase + i] = scol[wave][i];
    }
}

// Persistent phaser kernel: all 64 steps. Block b owns rows [8b, 8b+8);
// wave w owns row 8b+w with membrane potential in a register.
__global__ __launch_bounds__(PS_THREADS, 8) void persist_phaser(
        const unsigned* __restrict__ row_start, const unsigned* __restrict__ row_end,
        const float* __restrict__ val, const unsigned short* __restrict__ col,
        unsigned* __restrict__ mw,     // [2][1024] mask words (double-buffered)
        unsigned* __restrict__ gcnt,   // [32][64]  group arrival counters
        unsigned* __restrict__ garr,   // [64]      group-closer counters
        const float* __restrict__ v0, float* __restrict__ out) {
    __shared__ unsigned bits[N_NEURONS / 32];  // 1 KB
    __shared__ float sfire[8], sv[8];

    const int tid = threadIdx.x, wave = tid >> 6, lane = tid & 63;
    const int bb = blockIdx.x * 8;
    const int row = bb + wave;
    const int g = blockIdx.x >> 5;  // group of 32 blocks
    const unsigned s = row_start[row], e = row_end[row];
    float vr = v0[row];

    for (int t = 0; t < T_STEPS; ++t) {
        // Wait for phase t-1 (mask produced by all 1024 blocks). Step 0's mask
        // comes from init_state (kernel boundary = visible). Acquire load
        // invalidates this CU's L1 so the mask loads below read fresh L2 data.
        if (t > 0 && wave == 0) {
            while (__hip_atomic_load(&garr[t - 1], __ATOMIC_ACQUIRE,
                                     __HIP_MEMORY_SCOPE_AGENT) != PS_GROUPS)
                __builtin_amdgcn_s_sleep(8);
        }
        __syncthreads();

        // Stage mask into LDS: thread i<256 loads 4 mask words, packs 4 bytes.
        if (tid < 256) {
            const uint4 m4 = *(const uint4*)(mw + (t & 1) * PS_NBLOCKS + tid * 4);
            bits[tid] = (m4.x & 0xffu) | ((m4.y & 0xffu) << 8) |
                        ((m4.z & 0xffu) << 16) | ((m4.w & 0xffu) << 24);
        }
        __syncthreads();

        float acc = 0.f;
        for (unsigned k = s + (unsigned)lane * 4u; k < e; k += 256u) {
            float4 w = *(const float4*)(val + k);
            uint2 cc = *(const uint2*)(col + k);
            unsigned c0 = cc.x & 0xffffu, c1 = cc.x >> 16;
            unsigned c2 = cc.y & 0xffffu, c3 = cc.y >> 16;
            if ((bits[c0 >> 5] >> (c0 & 31)) & 1u) acc += w.x;
            if ((bits[c1 >> 5] >> (c1 & 31)) & 1u) acc += w.y;
            if ((bits[c2 >> 5] >> (c2 & 31)) & 1u) acc += w.z;
            if ((bits[c3 >> 5] >> (c3 & 31)) & 1u) acc += w.w;
        }
        #pragma unroll
        for (int off = 1; off < 64; off <<= 1) acc += __shfl_xor(acc, off);

        vr = DECAY * vr + acc;
        float f = (vr >= THRESH) ? 1.0f : 0.0f;
        if (lane == 0) { sfire[wave] = f; sv[wave] = vr; }
        vr = (f > 0.f) ? 0.f : vr;
        __syncthreads();

        // Publish this block's mask word, then arrive at phase t.
        if (tid == 0) {
            unsigned b8 = 0;
            #pragma unroll
            for (int i = 0; i < 8; ++i) b8 |= (sfire[i] > 0.f ? 1u : 0u) << i;
            mw[((t + 1) & 1) * PS_NBLOCKS + blockIdx.x] = b8;
            unsigned prev = __hip_atomic_fetch_add(&gcnt[g * T_STEPS + t], 1u,
                                                   __ATOMIC_ACQ_REL, __HIP_MEMORY_SCOPE_AGENT);
            if (prev == PS_GROUPS - 1)  // last arrival of this group
                __hip_atomic_fetch_add(&garr[t], 1u,
                                       __ATOMIC_ACQ_REL, __HIP_MEMORY_SCOPE_AGENT);
        }
        // Output writes overlap with other blocks' progress.
        if (tid < 8)
            out[(size_t)t * N_NEURONS + bb + tid] = sfire[tid];
        else if (tid < 16)
            out[(size_t)(T_STEPS + t) * N_NEURONS + bb + (tid - 8)] = sv[tid - 8];
    }
}

// ---- Dense fallback if ws is too small for CSR ----
__global__ __launch_bounds__(256) void step_dense(const float* __restrict__ W,
                                                  const float* __restrict__ fin,
                                                  float* __restrict__ fout,
                                                  float* __restrict__ v,
                                                  float* __restrict__ out_fire,
                                                  float* __restrict__ out_v) {
    __shared__ float fs[N_NEURONS];
    const float4* f4 = (const float4*)fin;
    float4* fs4 = (float4*)fs;
    #pragma unroll
    for (int k = 0; k < N_NEURONS / 4 / 256; ++k)
        fs4[k * 256 + threadIdx.x] = f4[k * 256 + threadIdx.x];
    __syncthreads();

    const int wave = threadIdx.x >> 6, lane = threadIdx.x & 63;
    const int row = blockIdx.x * 4 + wave;
    const float4* Wrow = (const float4*)(W + (size_t)row * N_NEURONS);

    float acc = 0.f;
    #pragma unroll 8
    for (int k = 0; k < N_NEURONS / 4 / 64; ++k) {
        const int idx = k * 64 + lane;
        float4 w = Wrow[idx];
        float4 f = fs4[idx];
        acc += w.x * f.x + w.y * f.y + w.z * f.z + w.w * f.w;
    }
    #pragma unroll
    for (int off = 32; off; off >>= 1) acc += __shfl_down(acc, off);

    if (lane == 0) {
        float vn   = DECAY * v[row] + acc;
        float fire = (vn >= THRESH) ? 1.0f : 0.0f;
        out_fire[row] = fire;
        out_v[row]    = vn;
        fout[row]     = fire;
        v[row]        = (fire > 0.f) ? 0.f : vn;
    }
}

extern "C" void kernel_launch(void* const* d_in, const int* in_sizes, int n_in,
                              void* d_out, int out_size, void* d_ws, size_t ws_size,
                              hipStream_t stream) {
    // inputs: x [T,N] (unused), W [N,N], f0 [N], v0 [N]
    const float* W  = (const float*)d_in[1];
    const float* f0 = (const float*)d_in[2];
    const float* v0 = (const float*)d_in[3];
    float* out = (float*)d_out;

    char* ws = (char*)d_ws;
    float* v   = (float*)(ws + WS_V_OFF);
    float* fb0 = (float*)(ws + WS_FB0_OFF);
    float* fb1 = (float*)(ws + WS_FB1_OFF);
    unsigned* mw      = (unsigned*)(ws + WS_MW_OFF);
    unsigned* gcnt    = (unsigned*)(ws + WS_GCNT_OFF);
    unsigned* garr    = (unsigned*)(ws + WS_GARR_OFF);
    unsigned* row_start = (unsigned*)(ws + WS_RS_OFF);
    unsigned* row_end   = (unsigned*)(ws + WS_RE_OFF);
    unsigned* counter   = (unsigned*)(ws + WS_CNT_OFF);
    float* val          = (float*)(ws + WS_VAL_OFF);
    unsigned short* col = (unsigned short*)(ws + WS_COL_OFF);

    init_state<<<(N_NEURONS + 255) / 256, 256, 0, stream>>>(
        f0, v0, v, fb0, mw, gcnt, garr, counter);

    if (ws_size >= WS_REQUIRED) {
        build_csr<<<N_NEURONS / 4, 256, 0, stream>>>(W, row_start, row_end, val, col, counter);
        persist_phaser<<<PS_NBLOCKS, PS_THREADS, 0, stream>>>(
            row_start, row_end, val, col, mw, gcnt, garr, v0, out);
    } else {
        float* fbufs[2] = {fb0, fb1};
        for (int t = 0; t < T_STEPS; ++t) {
            const float* fin = fbufs[t & 1];
            float* fout      = fbufs[(t + 1) & 1];
            step_dense<<<N_NEURONS / 4, 256, 0, stream>>>(
                W, fin, fout, v,
                out + (size_t)t * N_NEURONS,
                out + (size_t)(T_STEPS + t) * N_NEURONS);
        }
    }
}

// Round 6
// 577.996 us; speedup vs baseline: 5.9798x; 5.9798x over previous
//
#include <hip/hip_runtime.h>
#include <hip/hip_bf16.h>

// SpikingLayer: T=64 sequential LIF steps, cur = W @ f, W ~11% dense.
// Round-6: multi-launch (persistent grid-sync proven pathological on MI355X),
// adaptive per-step mode chosen device-side from firing-mask popcount:
//   mode 1 (z==0, all firing): cur = rowsum (precomputed)  -- ~zero traffic
//   mode 2 (0<z<=Z_CUT):       cur = rowsum - sum(non-firing w)  -- col stream only
//   mode 3 (z large):          full CSR gather (round-3 workhorse)
// Dynamics saturate to all-firing by t~3 (rowsum >= ~1.2 everywhere), so most
// steps are mode 1. Worst case degenerates to round-3 performance.
// Output layout (flat): fires[T][N] at 0, vs[T][N] at T*N.

#define N_NEURONS 8192
#define T_STEPS   64
#define DECAY     0.9f
#define THRESH    1.0f
#define NNZ_CAP   9437184u  // 14.06% density cap; actual ~11% + <=3/row pad
#define STAGE_CAP 1536      // max nnz/row ~1175 + pad
#define Z_CUT     320       // mode-2 threshold (scattered val loads beyond this)

// ws byte layout:
#define WS_V_OFF    0         // 8192 f32
#define WS_FB0_OFF  32768     // 8192 f32 (dense fallback)
#define WS_FB1_OFF  65536     // 8192 f32 (dense fallback)
#define WS_M0_OFF   98304     // 1024 B mask (bit i = neuron i firing)
#define WS_M1_OFF   99328     // 1024 B mask
#define WS_RSUM_OFF 100352    // 8192 f32 row sums
#define WS_RS_OFF   133120    // 8192 u32 row_start
#define WS_RE_OFF   165888    // 8192 u32 row_end
#define WS_CNT_OFF  198656    // u32 nnz counter (128B slot)
#define WS_VAL_OFF  198784    // NNZ_CAP f32 (16B aligned)
#define WS_COL_OFF  (WS_VAL_OFF + (size_t)NNZ_CAP * 4)
#define WS_REQUIRED (WS_COL_OFF + (size_t)NNZ_CAP * 2)

__global__ __launch_bounds__(256) void init_state(const float* __restrict__ f0,
                                                  const float* __restrict__ v0,
                                                  float* __restrict__ v,
                                                  float* __restrict__ fbuf0,
                                                  unsigned char* __restrict__ m0,
                                                  unsigned* __restrict__ counter) {
    int i = blockIdx.x * 256 + threadIdx.x;
    if (i < N_NEURONS) {
        v[i] = v0[i];
        fbuf0[i] = f0[i];
    }
    if (i < N_NEURONS / 8) {  // mask byte i covers neurons [8i, 8i+8)
        unsigned b = 0;
        #pragma unroll
        for (int j = 0; j < 8; ++j) b |= (f0[i * 8 + j] != 0.f ? 1u : 0u) << j;
        m0[i] = (unsigned char)b;
    }
    if (i == 0) *counter = 0u;
}

// Single-pass CSR build: coalesced float4 read, ballot-compaction into LDS
// (column order preserved), atomicAdd to claim the (4-padded) segment, then
// coalesced dump. Also computes rowsum with the step kernel's EXACT
// summation order (lane*4 + m*256 partition + butterfly), so mode-1 steps
// reproduce a full gather bit-for-bit.
__global__ __launch_bounds__(256) void build_csr(const float* __restrict__ W,
                                                 unsigned* __restrict__ row_start,
                                                 unsigned* __restrict__ row_end,
                                                 float* __restrict__ val,
                                                 unsigned short* __restrict__ col,
                                                 float* __restrict__ rowsum,
                                                 unsigned* __restrict__ counter) {
    __shared__ float          sval[4][STAGE_CAP];
    __shared__ unsigned short scol[4][STAGE_CAP];

    const int wave = threadIdx.x >> 6, lane = threadIdx.x & 63;
    const int row = blockIdx.x * 4 + wave;
    const float4* Wr = (const float4*)(W + (size_t)row * N_NEURONS);
    const unsigned long long lt = ((unsigned long long)1 << lane) - 1;

    unsigned cnt = 0;  // wave-uniform running nnz
    for (int k = 0; k < 32; ++k) {
        const int idx = k * 64 + lane;
        float4 w = Wr[idx];
        const int c0 = idx * 4;
        unsigned long long m;
        m = __ballot(w.x != 0.f);
        if (w.x != 0.f) { unsigned p = cnt + (unsigned)__popcll(m & lt); sval[wave][p] = w.x; scol[wave][p] = (unsigned short)c0; }
        cnt += (unsigned)__popcll(m);
        m = __ballot(w.y != 0.f);
        if (w.y != 0.f) { unsigned p = cnt + (unsigned)__popcll(m & lt); sval[wave][p] = w.y; scol[wave][p] = (unsigned short)(c0 + 1); }
        cnt += (unsigned)__popcll(m);
        m = __ballot(w.z != 0.f);
        if (w.z != 0.f) { unsigned p = cnt + (unsigned)__popcll(m & lt); sval[wave][p] = w.z; scol[wave][p] = (unsigned short)(c0 + 2); }
        cnt += (unsigned)__popcll(m);
        m = __ballot(w.w != 0.f);
        if (w.w != 0.f) { unsigned p = cnt + (unsigned)__popcll(m & lt); sval[wave][p] = w.w; scol[wave][p] = (unsigned short)(c0 + 3); }
        cnt += (unsigned)__popcll(m);
    }

    const unsigned padded = (cnt + 3u) & ~3u;  // float4/uint2 alignment in step
    if (lane < (int)(padded - cnt)) { sval[wave][cnt + lane] = 0.f; scol[wave][cnt + lane] = 0; }

    unsigned gbase = 0;
    if (lane == 0) gbase = atomicAdd(counter, padded);
    gbase = (unsigned)__shfl((int)gbase, 0);
    if (lane == 0) { row_start[row] = gbase; row_end[row] = gbase + padded; }
    __syncthreads();

    for (unsigned i = lane; i < padded; i += 64) {
        val[gbase + i] = sval[wave][i];
        col[gbase + i] = scol[wave][i];
    }

    // rowsum: replicate step_adaptive's mode-3 order exactly.
    float rsum = 0.f;
    for (unsigned i = (unsigned)lane * 4u; i < padded; i += 256u) {
        rsum += sval[wave][i];
        rsum += sval[wave][i + 1];
        rsum += sval[wave][i + 2];
        rsum += sval[wave][i + 3];
    }
    #pragma unroll
    for (int off = 1; off < 64; off <<= 1) rsum += __shfl_xor(rsum, off);
    if (lane == 0) rowsum[row] = rsum;
}

// Adaptive step: 1024 blocks x 512 threads, wave per row (8 rows/block).
// Mask (1 KB) staged in LDS; z = #non-firing decides the mode block-wide.
__global__ __launch_bounds__(512) void step_adaptive(
        const unsigned* __restrict__ row_start, const unsigned* __restrict__ row_end,
        const float* __restrict__ val, const unsigned short* __restrict__ col,
        const float* __restrict__ rowsum,
        const unsigned* __restrict__ min_mask, unsigned char* __restrict__ mout,
        float* __restrict__ v,
        float* __restrict__ out_fire, float* __restrict__ out_v) {
    __shared__ unsigned bits[N_NEURONS / 32];  // 1 KB
    __shared__ float sfire[8];
    __shared__ int kcnt;

    const int tid = threadIdx.x, wave = tid >> 6, lane = tid & 63;
    const int row = blockIdx.x * 8 + wave;

    if (tid == 0) kcnt = 0;
    __syncthreads();
    if (tid < N_NEURONS / 32) {
        unsigned w = min_mask[tid];
        bits[tid] = w;
        atomicAdd(&kcnt, __popc(w));  // integer: order-independent
    }
    __syncthreads();
    const int z = N_NEURONS - kcnt;

    const unsigned s = row_start[row], e = row_end[row];
    float acc = 0.f;

    if (z == 0) {
        // all firing: cur = rowsum, no CSR traffic
    } else if (z <= Z_CUT) {
        // subtractive: scan col stream, load vals only for quads with a zero bit
        for (unsigned k = s + (unsigned)lane * 4u; k < e; k += 256u) {
            uint2 cc = *(const uint2*)(col + k);
            unsigned c0 = cc.x & 0xffffu, c1 = cc.x >> 16;
            unsigned c2 = cc.y & 0xffffu, c3 = cc.y >> 16;
            unsigned b0 = (bits[c0 >> 5] >> (c0 & 31)) & 1u;
            unsigned b1 = (bits[c1 >> 5] >> (c1 & 31)) & 1u;
            unsigned b2 = (bits[c2 >> 5] >> (c2 & 31)) & 1u;
            unsigned b3 = (bits[c3 >> 5] >> (c3 & 31)) & 1u;
            if (!(b0 & b1 & b2 & b3)) {
                float4 w = *(const float4*)(val + k);
                if (!b0) acc += w.x;
                if (!b1) acc += w.y;
                if (!b2) acc += w.z;
                if (!b3) acc += w.w;
            }
        }
    } else {
        // full gather (round-3 workhorse)
        for (unsigned k = s + (unsigned)lane * 4u; k < e; k += 256u) {
            float4 w = *(const float4*)(val + k);
            uint2 cc = *(const uint2*)(col + k);
            unsigned c0 = cc.x & 0xffffu, c1 = cc.x >> 16;
            unsigned c2 = cc.y & 0xffffu, c3 = cc.y >> 16;
            if ((bits[c0 >> 5] >> (c0 & 31)) & 1u) acc += w.x;
            if ((bits[c1 >> 5] >> (c1 & 31)) & 1u) acc += w.y;
            if ((bits[c2 >> 5] >> (c2 & 31)) & 1u) acc += w.z;
            if ((bits[c3 >> 5] >> (c3 & 31)) & 1u) acc += w.w;
        }
    }
    #pragma unroll
    for (int off = 1; off < 64; off <<= 1) acc += __shfl_xor(acc, off);

    if (lane == 0) {
        float cur = (z > Z_CUT) ? acc : (rowsum[row] - acc);  // z==0: acc==0
        float vn   = DECAY * v[row] + cur;
        float fire = (vn >= THRESH) ? 1.0f : 0.0f;
        out_fire[row] = fire;
        out_v[row]    = vn;
        v[row]        = (fire > 0.f) ? 0.f : vn;
        sfire[wave]   = fire;
    }
    __syncthreads();
    if (tid == 0) {
        unsigned b8 = 0;
        #pragma unroll
        for (int i = 0; i < 8; ++i) b8 |= (sfire[i] > 0.f ? 1u : 0u) << i;
        mout[blockIdx.x] = (unsigned char)b8;
    }
}

// ---- Dense fallback if ws is too small for CSR ----
__global__ __launch_bounds__(256) void step_dense(const float* __restrict__ W,
                                                  const float* __restrict__ fin,
                                                  float* __restrict__ fout,
                                                  float* __restrict__ v,
                                                  float* __restrict__ out_fire,
                                                  float* __restrict__ out_v) {
    __shared__ float fs[N_NEURONS];
    const float4* f4 = (const float4*)fin;
    float4* fs4 = (float4*)fs;
    #pragma unroll
    for (int k = 0; k < N_NEURONS / 4 / 256; ++k)
        fs4[k * 256 + threadIdx.x] = f4[k * 256 + threadIdx.x];
    __syncthreads();

    const int wave = threadIdx.x >> 6, lane = threadIdx.x & 63;
    const int row = blockIdx.x * 4 + wave;
    const float4* Wrow = (const float4*)(W + (size_t)row * N_NEURONS);

    float acc = 0.f;
    #pragma unroll 8
    for (int k = 0; k < N_NEURONS / 4 / 64; ++k) {
        const int idx = k * 64 + lane;
        float4 w = Wrow[idx];
        float4 f = fs4[idx];
        acc += w.x * f.x + w.y * f.y + w.z * f.z + w.w * f.w;
    }
    #pragma unroll
    for (int off = 32; off; off >>= 1) acc += __shfl_down(acc, off);

    if (lane == 0) {
        float vn   = DECAY * v[row] + acc;
        float fire = (vn >= THRESH) ? 1.0f : 0.0f;
        out_fire[row] = fire;
        out_v[row]    = vn;
        fout[row]     = fire;
        v[row]        = (fire > 0.f) ? 0.f : vn;
    }
}

extern "C" void kernel_launch(void* const* d_in, const int* in_sizes, int n_in,
                              void* d_out, int out_size, void* d_ws, size_t ws_size,
                              hipStream_t stream) {
    // inputs: x [T,N] (unused), W [N,N], f0 [N], v0 [N]
    const float* W  = (const float*)d_in[1];
    const float* f0 = (const float*)d_in[2];
    const float* v0 = (const float*)d_in[3];
    float* out = (float*)d_out;

    char* ws = (char*)d_ws;
    float* v   = (float*)(ws + WS_V_OFF);
    float* fb0 = (float*)(ws + WS_FB0_OFF);
    float* fb1 = (float*)(ws + WS_FB1_OFF);
    unsigned char* m0 = (unsigned char*)(ws + WS_M0_OFF);
    unsigned char* m1 = (unsigned char*)(ws + WS_M1_OFF);
    float* rowsum       = (float*)(ws + WS_RSUM_OFF);
    unsigned* row_start = (unsigned*)(ws + WS_RS_OFF);
    unsigned* row_end   = (unsigned*)(ws + WS_RE_OFF);
    unsigned* counter   = (unsigned*)(ws + WS_CNT_OFF);
    float* val          = (float*)(ws + WS_VAL_OFF);
    unsigned short* col = (unsigned short*)(ws + WS_COL_OFF);

    init_state<<<(N_NEURONS + 255) / 256, 256, 0, stream>>>(
        f0, v0, v, fb0, m0, counter);

    if (ws_size >= WS_REQUIRED) {
        build_csr<<<N_NEURONS / 4, 256, 0, stream>>>(
            W, row_start, row_end, val, col, rowsum, counter);
        unsigned char* masks[2] = {m0, m1};
        for (int t = 0; t < T_STEPS; ++t) {
            const unsigned* min_mask = (const unsigned*)masks[t & 1];
            unsigned char* mout      = masks[(t + 1) & 1];
            step_adaptive<<<N_NEURONS / 8, 512, 0, stream>>>(
                row_start, row_end, val, col, rowsum, min_mask, mout, v,
                out + (size_t)t * N_NEURONS,
                out + (size_t)(T_STEPS + t) * N_NEURONS);
        }
    } else {
        float* fbufs[2] = {fb0, fb1};
        for (int t = 0; t < T_STEPS; ++t) {
            const float* fin = fbufs[t & 1];
            float* fout      = fbufs[(t + 1) & 1];
            step_dense<<<N_NEURONS / 4, 256, 0, stream>>>(
                W, fin, fout, v,
                out + (size_t)t * N_NEURONS,
                out + (size_t)(T_STEPS + t) * N_NEURONS);
        }
    }
}

// Round 7
// 433.807 us; speedup vs baseline: 7.9674x; 1.3324x over previous
//
#include <hip/hip_runtime.h>
#include <hip/hip_bf16.h>

// SpikingLayer: T=64 sequential LIF steps, cur = W @ f, W ~12% dense.
// Round-7:
//   build_csr: per-lane count + wave-scan + direct global writes (no ballot
//     chain). Entry order lane-major but deterministic. rowsum computed from
//     an LDS copy in the step kernel's exact gather order; min(rowsum) via
//     int atomicMin (positive floats).
//   step_adaptive (z = #non-firing from mask popcount):
//     z==0 && minrs>=1 : absorbing -> fill ALL remaining outputs (fire=1,
//                        v=rowsum, bit-exact vs gather), set done flag;
//                        later launches early-exit on one scalar read.
//     z==0 (minrs<1)   : cur = rowsum.
//     0<z<=128         : cur = rowsum - sum_{j nonfiring} W[row][j] (dense
//                        column reads, ascending-j deterministic order).
//     else             : full CSR gather.
// Output layout (flat): fires[T][N] at 0, vs[T][N] at T*N.

#define N_NEURONS 8192
#define T_STEPS   64
#define DECAY     0.9f
#define THRESH    1.0f
#define NNZ_CAP   9437184u
#define STAGE_CAP 1536      // max nnz/row ~1175 (mean ~1030) + margin
#define ZS_CUT    128       // dense-column subtract threshold

#define SB_BLOCKS  512      // step grid: 16 rows/block, 8 waves, 2 rows/wave
#define SB_THREADS 512

// ws byte layout:
#define WS_V_OFF    0         // 8192 f32
#define WS_FB0_OFF  32768     // 8192 f32 (dense fallback)
#define WS_FB1_OFF  65536     // 8192 f32 (dense fallback)
#define WS_M0_OFF   98304     // 1024 B mask (bit n = neuron n firing)
#define WS_M1_OFF   99328     // 1024 B mask
#define WS_RSUM_OFF 100352    // 8192 f32 row sums
#define WS_RS_OFF   133120    // 8192 u32 row_start
#define WS_RE_OFF   165888    // 8192 u32 row_end
#define WS_CNT_OFF  198656    // u32 nnz counter
#define WS_DONE_OFF 198784    // u32 done flag
#define WS_MRS_OFF  198912    // i32 min-rowsum bits
#define WS_VAL_OFF  199040    // NNZ_CAP f32 (16B aligned)
#define WS_COL_OFF  (WS_VAL_OFF + (size_t)NNZ_CAP * 4)
#define WS_REQUIRED (WS_COL_OFF + (size_t)NNZ_CAP * 2)

__global__ __launch_bounds__(256) void init_state(const float* __restrict__ f0,
                                                  const float* __restrict__ v0,
                                                  float* __restrict__ v,
                                                  float* __restrict__ fbuf0,
                                                  unsigned short* __restrict__ m0,
                                                  unsigned* __restrict__ counter,
                                                  unsigned* __restrict__ done,
                                                  int* __restrict__ mrs) {
    int i = blockIdx.x * 256 + threadIdx.x;
    if (i < N_NEURONS) {
        v[i] = v0[i];
        fbuf0[i] = f0[i];
    }
    if (i < N_NEURONS / 16) {  // mask ushort i covers neurons [16i, 16i+16)
        unsigned b = 0;
        #pragma unroll
        for (int j = 0; j < 16; ++j) b |= (f0[i * 16 + j] != 0.f ? 1u : 0u) << j;
        m0[i] = (unsigned short)b;
    }
    if (i == 0) { *counter = 0u; *done = 0u; *mrs = 0x7F7FFFFF; }  // FLT_MAX
}

// CSR build: wave per row (4 rows/block of 256).
__global__ __launch_bounds__(256) void build_csr(const float* __restrict__ W,
                                                 unsigned* __restrict__ row_start,
                                                 unsigned* __restrict__ row_end,
                                                 float* __restrict__ val,
                                                 unsigned short* __restrict__ col,
                                                 float* __restrict__ rowsum,
                                                 unsigned* __restrict__ counter,
                                                 int* __restrict__ mrs) {
    __shared__ float sval[4][STAGE_CAP];

    const int wave = threadIdx.x >> 6, lane = threadIdx.x & 63;
    const int row = blockIdx.x * 4 + wave;
    const float4* Wr = (const float4*)(W + (size_t)row * N_NEURONS);

    // Pass 1: per-lane count (independent iterations -> deep ILP)
    int c = 0;
    #pragma unroll 8
    for (int k = 0; k < 32; ++k) {
        float4 w = Wr[k * 64 + lane];
        c += (w.x != 0.f) + (w.y != 0.f) + (w.z != 0.f) + (w.w != 0.f);
    }
    // inclusive wave scan
    int incl = c;
    #pragma unroll
    for (int off = 1; off < 64; off <<= 1) {
        int n = __shfl_up(incl, off);
        if (lane >= off) incl += n;
    }
    const unsigned total  = (unsigned)__shfl(incl, 63);
    const unsigned padded = (total + 3u) & ~3u;

    unsigned gbase = 0;
    if (lane == 63) gbase = atomicAdd(counter, padded);
    gbase = (unsigned)__shfl((int)gbase, 63);
    if (lane == 0) { row_start[row] = gbase; row_end[row] = gbase + padded; }

    // Pass 2: re-read (L2-hot), lane writes its contiguous run [loff, loff+c)
    unsigned p = (unsigned)(incl - c);
    #pragma unroll 4
    for (int k = 0; k < 32; ++k) {
        const int idx = k * 64 + lane;
        float4 w = Wr[idx];
        const int c0 = idx * 4;
        if (w.x != 0.f) { val[gbase + p] = w.x; col[gbase + p] = (unsigned short)c0;       sval[wave][p] = w.x; ++p; }
        if (w.y != 0.f) { val[gbase + p] = w.y; col[gbase + p] = (unsigned short)(c0 + 1); sval[wave][p] = w.y; ++p; }
        if (w.z != 0.f) { val[gbase + p] = w.z; col[gbase + p] = (unsigned short)(c0 + 2); sval[wave][p] = w.z; ++p; }
        if (w.w != 0.f) { val[gbase + p] = w.w; col[gbase + p] = (unsigned short)(c0 + 3); sval[wave][p] = w.w; ++p; }
    }
    if (lane < (int)(padded - total)) {  // zero pads
        val[gbase + total + lane] = 0.f;
        col[gbase + total + lane] = 0;
        sval[wave][total + lane]  = 0.f;
    }
    __syncthreads();  // LDS visibility across lanes

    // rowsum in the step kernel's exact gather order
    float rsum = 0.f;
    for (unsigned i = (unsigned)lane * 4u; i < padded; i += 256u) {
        rsum += sval[wave][i];
        rsum += sval[wave][i + 1];
        rsum += sval[wave][i + 2];
        rsum += sval[wave][i + 3];
    }
    #pragma unroll
    for (int off = 1; off < 64; off <<= 1) rsum += __shfl_xor(rsum, off);
    if (lane == 0) {
        rowsum[row] = rsum;
        atomicMin(mrs, __float_as_int(rsum));  // rsum > 0: int order == float order
    }
}

// Adaptive step. 512 blocks x 512 threads; block owns 16 rows; wave owns 2.
__global__ __launch_bounds__(SB_THREADS) void step_adaptive(
        const unsigned* __restrict__ row_start, const unsigned* __restrict__ row_end,
        const float* __restrict__ val, const unsigned short* __restrict__ col,
        const float* __restrict__ rowsum, const float* __restrict__ W,
        const unsigned* __restrict__ min_mask, unsigned short* __restrict__ mout,
        float* __restrict__ v, float* __restrict__ out,
        unsigned* __restrict__ done, const int* __restrict__ mrs, int t) {
    if (*done) return;  // absorbing state already filled

    __shared__ unsigned bits[N_NEURONS / 32];  // 1 KB
    __shared__ float sfire[16];
    __shared__ int kcnt, wpart[4];
    __shared__ unsigned short zlist[ZS_CUT];

    const int tid = threadIdx.x, wave = tid >> 6, lane = tid & 63;
    const int bb = blockIdx.x * 16;
    const int r0 = bb + wave * 2, r1 = r0 + 1;

    if (tid == 0) kcnt = 0;
    __syncthreads();
    if (tid < 256) {
        unsigned w = min_mask[tid];
        bits[tid] = w;
        atomicAdd(&kcnt, __popc(w));
    }
    __syncthreads();
    const int z = N_NEURONS - kcnt;
    const float minrs = __int_as_float(*mrs);

    if (z == 0 && minrs >= THRESH) {
        // Absorbing: all rows fired last step => v==0 everywhere. Every
        // remaining step: fire=1, v_pre=rowsum (bit-exact), v resets to 0.
        if (tid < 16) {
            const float rs = rowsum[bb + tid];
            for (int tt = t; tt < T_STEPS; ++tt) {
                out[(size_t)tt * N_NEURONS + bb + tid] = 1.0f;
                out[(size_t)(T_STEPS + tt) * N_NEURONS + bb + tid] = rs;
            }
        }
        __syncthreads();
        if (tid == 0) *done = 1u;
        return;
    }

    float acc0 = 0.f, acc1 = 0.f;
    const bool subtractive = (z <= ZS_CUT);  // includes z==0 (acc stays 0)

    if (z > 0 && z <= ZS_CUT) {
        // Deterministic ascending zero-list via block scan over 256 words.
        int zc = 0, word = 0, incl = 0;
        if (tid < 256) {
            word = (int)bits[tid];
            zc = 32 - __popc((unsigned)word);
            incl = zc;
            #pragma unroll
            for (int off = 1; off < 64; off <<= 1) {
                int n = __shfl_up(incl, off);
                if (lane >= off) incl += n;
            }
            if (lane == 63) wpart[wave] = incl;
        }
        __syncthreads();
        if (tid < 256) {
            int base = 0;
            for (int wv = 0; wv < wave; ++wv) base += wpart[wv];
            int off = base + incl - zc;
            for (int b = 0; b < 32; ++b)
                if (!((word >> b) & 1)) zlist[off++] = (unsigned short)(tid * 32 + b);
        }
        __syncthreads();
        // Dense-column subtraction, ascending j per lane (deterministic).
        const float* Wr0 = W + (size_t)r0 * N_NEURONS;
        const float* Wr1 = W + (size_t)r1 * N_NEURONS;
        for (int i = lane; i < z; i += 64) {
            const int j = zlist[i];
            acc0 += Wr0[j];
            acc1 += Wr1[j];
        }
    } else if (z > ZS_CUT) {
        // Full CSR gather.
        const unsigned s0 = row_start[r0], e0 = row_end[r0];
        for (unsigned k = s0 + (unsigned)lane * 4u; k < e0; k += 256u) {
            float4 w = *(const float4*)(val + k);
            uint2 cc = *(const uint2*)(col + k);
            unsigned c0 = cc.x & 0xffffu, c1 = cc.x >> 16;
            unsigned c2 = cc.y & 0xffffu, c3 = cc.y >> 16;
            if ((bits[c0 >> 5] >> (c0 & 31)) & 1u) acc0 += w.x;
            if ((bits[c1 >> 5] >> (c1 & 31)) & 1u) acc0 += w.y;
            if ((bits[c2 >> 5] >> (c2 & 31)) & 1u) acc0 += w.z;
            if ((bits[c3 >> 5] >> (c3 & 31)) & 1u) acc0 += w.w;
        }
        const unsigned s1 = row_start[r1], e1 = row_end[r1];
        for (unsigned k = s1 + (unsigned)lane * 4u; k < e1; k += 256u) {
            float4 w = *(const float4*)(val + k);
            uint2 cc = *(const uint2*)(col + k);
            unsigned c0 = cc.x & 0xffffu, c1 = cc.x >> 16;
            unsigned c2 = cc.y & 0xffffu, c3 = cc.y >> 16;
            if ((bits[c0 >> 5] >> (c0 & 31)) & 1u) acc1 += w.x;
            if ((bits[c1 >> 5] >> (c1 & 31)) & 1u) acc1 += w.y;
            if ((bits[c2 >> 5] >> (c2 & 31)) & 1u) acc1 += w.z;
            if ((bits[c3 >> 5] >> (c3 & 31)) & 1u) acc1 += w.w;
        }
    }
    #pragma unroll
    for (int off = 1; off < 64; off <<= 1) {
        acc0 += __shfl_xor(acc0, off);
        acc1 += __shfl_xor(acc1, off);
    }

    if (lane == 0) {
        float cur0 = subtractive ? (rowsum[r0] - acc0) : acc0;
        float cur1 = subtractive ? (rowsum[r1] - acc1) : acc1;
        float vn0 = DECAY * v[r0] + cur0;
        float vn1 = DECAY * v[r1] + cur1;
        float f0 = (vn0 >= THRESH) ? 1.0f : 0.0f;
        float f1 = (vn1 >= THRESH) ? 1.0f : 0.0f;
        out[(size_t)t * N_NEURONS + r0] = f0;
        out[(size_t)t * N_NEURONS + r1] = f1;
        out[(size_t)(T_STEPS + t) * N_NEURONS + r0] = vn0;
        out[(size_t)(T_STEPS + t) * N_NEURONS + r1] = vn1;
        v[r0] = (f0 > 0.f) ? 0.f : vn0;
        v[r1] = (f1 > 0.f) ? 0.f : vn1;
        sfire[wave * 2] = f0;
        sfire[wave * 2 + 1] = f1;
    }
    __syncthreads();
    if (tid == 0) {
        unsigned b16 = 0;
        #pragma unroll
        for (int i = 0; i < 16; ++i) b16 |= (sfire[i] > 0.f ? 1u : 0u) << i;
        mout[blockIdx.x] = (unsigned short)b16;
    }
}

// ---- Dense fallback if ws is too small for CSR ----
__global__ __launch_bounds__(256) void step_dense(const float* __restrict__ W,
                                                  const float* __restrict__ fin,
                                                  float* __restrict__ fout,
                                                  float* __restrict__ v,
                                                  float* __restrict__ out_fire,
                                                  float* __restrict__ out_v) {
    __shared__ float fs[N_NEURONS];
    const float4* f4 = (const float4*)fin;
    float4* fs4 = (float4*)fs;
    #pragma unroll
    for (int k = 0; k < N_NEURONS / 4 / 256; ++k)
        fs4[k * 256 + threadIdx.x] = f4[k * 256 + threadIdx.x];
    __syncthreads();

    const int wave = threadIdx.x >> 6, lane = threadIdx.x & 63;
    const int row = blockIdx.x * 4 + wave;
    const float4* Wrow = (const float4*)(W + (size_t)row * N_NEURONS);

    float acc = 0.f;
    #pragma unroll 8
    for (int k = 0; k < N_NEURONS / 4 / 64; ++k) {
        const int idx = k * 64 + lane;
        float4 w = Wrow[idx];
        float4 f = fs4[idx];
        acc += w.x * f.x + w.y * f.y + w.z * f.z + w.w * f.w;
    }
    #pragma unroll
    for (int off = 32; off; off >>= 1) acc += __shfl_down(acc, off);

    if (lane == 0) {
        float vn   = DECAY * v[row] + acc;
        float fire = (vn >= THRESH) ? 1.0f : 0.0f;
        out_fire[row] = fire;
        out_v[row]    = vn;
        fout[row]     = fire;
        v[row]        = (fire > 0.f) ? 0.f : vn;
    }
}

extern "C" void kernel_launch(void* const* d_in, const int* in_sizes, int n_in,
                              void* d_out, int out_size, void* d_ws, size_t ws_size,
                              hipStream_t stream) {
    const float* W  = (const float*)d_in[1];
    const float* f0 = (const float*)d_in[2];
    const float* v0 = (const float*)d_in[3];
    float* out = (float*)d_out;

    char* ws = (char*)d_ws;
    float* v   = (float*)(ws + WS_V_OFF);
    float* fb0 = (float*)(ws + WS_FB0_OFF);
    float* fb1 = (float*)(ws + WS_FB1_OFF);
    unsigned short* m0 = (unsigned short*)(ws + WS_M0_OFF);
    unsigned short* m1 = (unsigned short*)(ws + WS_M1_OFF);
    float* rowsum       = (float*)(ws + WS_RSUM_OFF);
    unsigned* row_start = (unsigned*)(ws + WS_RS_OFF);
    unsigned* row_end   = (unsigned*)(ws + WS_RE_OFF);
    unsigned* counter   = (unsigned*)(ws + WS_CNT_OFF);
    unsigned* done      = (unsigned*)(ws + WS_DONE_OFF);
    int* mrs            = (int*)(ws + WS_MRS_OFF);
    float* val          = (float*)(ws + WS_VAL_OFF);
    unsigned short* col = (unsigned short*)(ws + WS_COL_OFF);

    init_state<<<(N_NEURONS + 255) / 256, 256, 0, stream>>>(
        f0, v0, v, fb0, m0, counter, done, mrs);

    if (ws_size >= WS_REQUIRED) {
        build_csr<<<N_NEURONS / 4, 256, 0, stream>>>(
            W, row_start, row_end, val, col, rowsum, counter, mrs);
        unsigned short* masks[2] = {m0, m1};
        for (int t = 0; t < T_STEPS; ++t) {
            step_adaptive<<<SB_BLOCKS, SB_THREADS, 0, stream>>>(
                row_start, row_end, val, col, rowsum, W,
                (const unsigned*)masks[t & 1], masks[(t + 1) & 1],
                v, out, done, mrs, t);
        }
    } else {
        float* fbufs[2] = {fb0, fb1};
        for (int t = 0; t < T_STEPS; ++t) {
            const float* fin = fbufs[t & 1];
            float* fout      = fbufs[(t + 1) & 1];
            step_dense<<<N_NEURONS / 4, 256, 0, stream>>>(
                W, fin, fout, v,
                out + (size_t)t * N_NEURONS,
                out + (size_t)(T_STEPS + t) * N_NEURONS);
        }
    }
}

// Round 8
// 349.239 us; speedup vs baseline: 9.8967x; 1.2421x over previous
//
#include <hip/hip_runtime.h>
#include <hip/hip_bf16.h>

// SpikingLayer: T=64 sequential LIF steps, cur = W @ f, W ~12% dense.
// Round-8: build_csr = coalesced lane-interleaved reads (round 7) + LDS
// staging + coalesced vectorized dump (fixes round 7's 7x write
// amplification from per-lane scattered global stores).
//   step_adaptive (z = #non-firing from mask popcount):
//     z==0 && minrs>=1 : absorbing -> fill ALL remaining outputs (fire=1,
//                        v=rowsum, bit-exact vs gather), set done flag;
//                        later launches early-exit on one scalar read.
//     z==0 (minrs<1)   : cur = rowsum.
//     0<z<=128         : cur = rowsum - sum_{j nonfiring} W[row][j].
//     else             : full CSR gather.
// Output layout (flat): fires[T][N] at 0, vs[T][N] at T*N.

#define N_NEURONS 8192
#define T_STEPS   64
#define DECAY     0.9f
#define THRESH    1.0f
#define NNZ_CAP   9437184u
#define STAGE_CAP 1536      // max nnz/row ~1175 (mean ~1030) + margin
#define ZS_CUT    128       // dense-column subtract threshold

#define SB_BLOCKS  512      // step grid: 16 rows/block, 8 waves, 2 rows/wave
#define SB_THREADS 512

// ws byte layout:
#define WS_V_OFF    0         // 8192 f32
#define WS_FB0_OFF  32768     // 8192 f32 (dense fallback)
#define WS_FB1_OFF  65536     // 8192 f32 (dense fallback)
#define WS_M0_OFF   98304     // 1024 B mask (bit n = neuron n firing)
#define WS_M1_OFF   99328     // 1024 B mask
#define WS_RSUM_OFF 100352    // 8192 f32 row sums
#define WS_RS_OFF   133120    // 8192 u32 row_start
#define WS_RE_OFF   165888    // 8192 u32 row_end
#define WS_CNT_OFF  198656    // u32 nnz counter
#define WS_DONE_OFF 198784    // u32 done flag
#define WS_MRS_OFF  198912    // i32 min-rowsum bits
#define WS_VAL_OFF  199040    // NNZ_CAP f32 (16B aligned)
#define WS_COL_OFF  (WS_VAL_OFF + (size_t)NNZ_CAP * 4)
#define WS_REQUIRED (WS_COL_OFF + (size_t)NNZ_CAP * 2)

__global__ __launch_bounds__(256) void init_state(const float* __restrict__ f0,
                                                  const float* __restrict__ v0,
                                                  float* __restrict__ v,
                                                  float* __restrict__ fbuf0,
                                                  unsigned short* __restrict__ m0,
                                                  unsigned* __restrict__ counter,
                                                  unsigned* __restrict__ done,
                                                  int* __restrict__ mrs) {
    int i = blockIdx.x * 256 + threadIdx.x;
    if (i < N_NEURONS) {
        v[i] = v0[i];
        fbuf0[i] = f0[i];
    }
    if (i < N_NEURONS / 16) {  // mask ushort i covers neurons [16i, 16i+16)
        unsigned b = 0;
        #pragma unroll
        for (int j = 0; j < 16; ++j) b |= (f0[i * 16 + j] != 0.f ? 1u : 0u) << j;
        m0[i] = (unsigned short)b;
    }
    if (i == 0) { *counter = 0u; *done = 0u; *mrs = 0x7F7FFFFF; }  // FLT_MAX
}

// CSR build: wave per row (4 rows/block of 256). Coalesced reads, LDS
// compaction (per-lane runs at wave-scanned offsets), coalesced vector dump.
__global__ __launch_bounds__(256) void build_csr(const float* __restrict__ W,
                                                 unsigned* __restrict__ row_start,
                                                 unsigned* __restrict__ row_end,
                                                 float* __restrict__ val,
                                                 unsigned short* __restrict__ col,
                                                 float* __restrict__ rowsum,
                                                 unsigned* __restrict__ counter,
                                                 int* __restrict__ mrs) {
    __shared__ float          sval[4][STAGE_CAP];
    __shared__ unsigned short scol[4][STAGE_CAP];

    const int wave = threadIdx.x >> 6, lane = threadIdx.x & 63;
    const int row = blockIdx.x * 4 + wave;
    const float4* Wr = (const float4*)(W + (size_t)row * N_NEURONS);

    // Pass 1: per-lane count (independent iterations -> deep ILP)
    int c = 0;
    #pragma unroll 8
    for (int k = 0; k < 32; ++k) {
        float4 w = Wr[k * 64 + lane];
        c += (w.x != 0.f) + (w.y != 0.f) + (w.z != 0.f) + (w.w != 0.f);
    }
    // inclusive wave scan
    int incl = c;
    #pragma unroll
    for (int off = 1; off < 64; off <<= 1) {
        int n = __shfl_up(incl, off);
        if (lane >= off) incl += n;
    }
    const unsigned total  = (unsigned)__shfl(incl, 63);
    const unsigned padded = (total + 3u) & ~3u;

    unsigned gbase = 0;
    if (lane == 63) gbase = atomicAdd(counter, padded);
    gbase = (unsigned)__shfl((int)gbase, 63);
    if (lane == 0) { row_start[row] = gbase; row_end[row] = gbase + padded; }

    // Pass 2: re-read (L3-hot), compact into LDS at per-lane run [loff,loff+c)
    unsigned p = (unsigned)(incl - c);
    #pragma unroll 4
    for (int k = 0; k < 32; ++k) {
        const int idx = k * 64 + lane;
        float4 w = Wr[idx];
        const int c0 = idx * 4;
        if (w.x != 0.f) { sval[wave][p] = w.x; scol[wave][p] = (unsigned short)c0;       ++p; }
        if (w.y != 0.f) { sval[wave][p] = w.y; scol[wave][p] = (unsigned short)(c0 + 1); ++p; }
        if (w.z != 0.f) { sval[wave][p] = w.z; scol[wave][p] = (unsigned short)(c0 + 2); ++p; }
        if (w.w != 0.f) { sval[wave][p] = w.w; scol[wave][p] = (unsigned short)(c0 + 3); ++p; }
    }
    if (lane < (int)(padded - total)) {  // zero pads
        sval[wave][total + lane] = 0.f;
        scol[wave][total + lane] = 0;
    }
    __syncthreads();

    // Coalesced dump: float4 val stores (1 KiB/wave/instr), packed-u32 cols.
    float4* val4 = (float4*)(val + gbase);            // gbase % 4 == 0
    for (unsigned i = lane; i < padded / 4u; i += 64) {
        val4[i] = make_float4(sval[wave][i * 4], sval[wave][i * 4 + 1],
                              sval[wave][i * 4 + 2], sval[wave][i * 4 + 3]);
    }
    unsigned* col2 = (unsigned*)(col + gbase);        // 4B aligned
    for (unsigned i = lane; i < padded / 2u; i += 64) {
        col2[i] = (unsigned)scol[wave][i * 2] | ((unsigned)scol[wave][i * 2 + 1] << 16);
    }

    // rowsum in the step kernel's exact gather order
    float rsum = 0.f;
    for (unsigned i = (unsigned)lane * 4u; i < padded; i += 256u) {
        rsum += sval[wave][i];
        rsum += sval[wave][i + 1];
        rsum += sval[wave][i + 2];
        rsum += sval[wave][i + 3];
    }
    #pragma unroll
    for (int off = 1; off < 64; off <<= 1) rsum += __shfl_xor(rsum, off);
    if (lane == 0) {
        rowsum[row] = rsum;
        atomicMin(mrs, __float_as_int(rsum));  // rsum > 0: int order == float order
    }
}

// Adaptive step. 512 blocks x 512 threads; block owns 16 rows; wave owns 2.
__global__ __launch_bounds__(SB_THREADS) void step_adaptive(
        const unsigned* __restrict__ row_start, const unsigned* __restrict__ row_end,
        const float* __restrict__ val, const unsigned short* __restrict__ col,
        const float* __restrict__ rowsum, const float* __restrict__ W,
        const unsigned* __restrict__ min_mask, unsigned short* __restrict__ mout,
        float* __restrict__ v, float* __restrict__ out,
        unsigned* __restrict__ done, const int* __restrict__ mrs, int t) {
    if (*done) return;  // absorbing state already filled

    __shared__ unsigned bits[N_NEURONS / 32];  // 1 KB
    __shared__ float sfire[16];
    __shared__ int kcnt, wpart[4];
    __shared__ unsigned short zlist[ZS_CUT];

    const int tid = threadIdx.x, wave = tid >> 6, lane = tid & 63;
    const int bb = blockIdx.x * 16;
    const int r0 = bb + wave * 2, r1 = r0 + 1;

    if (tid == 0) kcnt = 0;
    __syncthreads();
    if (tid < 256) {
        unsigned w = min_mask[tid];
        bits[tid] = w;
        atomicAdd(&kcnt, __popc(w));
    }
    __syncthreads();
    const int z = N_NEURONS - kcnt;
    const float minrs = __int_as_float(*mrs);

    if (z == 0 && minrs >= THRESH) {
        // Absorbing: all rows fired last step => v==0 everywhere. Every
        // remaining step: fire=1, v_pre=rowsum (bit-exact), v resets to 0.
        if (tid < 16) {
            const float rs = rowsum[bb + tid];
            for (int tt = t; tt < T_STEPS; ++tt) {
                out[(size_t)tt * N_NEURONS + bb + tid] = 1.0f;
                out[(size_t)(T_STEPS + tt) * N_NEURONS + bb + tid] = rs;
            }
        }
        __syncthreads();
        if (tid == 0) *done = 1u;
        return;
    }

    float acc0 = 0.f, acc1 = 0.f;
    const bool subtractive = (z <= ZS_CUT);  // includes z==0 (acc stays 0)

    if (z > 0 && z <= ZS_CUT) {
        // Deterministic ascending zero-list via block scan over 256 words.
        int zc = 0, word = 0, incl = 0;
        if (tid < 256) {
            word = (int)bits[tid];
            zc = 32 - __popc((unsigned)word);
            incl = zc;
            #pragma unroll
            for (int off = 1; off < 64; off <<= 1) {
                int n = __shfl_up(incl, off);
                if (lane >= off) incl += n;
            }
            if (lane == 63) wpart[wave] = incl;
        }
        __syncthreads();
        if (tid < 256) {
            int base = 0;
            for (int wv = 0; wv < wave; ++wv) base += wpart[wv];
            int off = base + incl - zc;
            for (int b = 0; b < 32; ++b)
                if (!((word >> b) & 1)) zlist[off++] = (unsigned short)(tid * 32 + b);
        }
        __syncthreads();
        // Dense-column subtraction, ascending j per lane (deterministic).
        const float* Wr0 = W + (size_t)r0 * N_NEURONS;
        const float* Wr1 = W + (size_t)r1 * N_NEURONS;
        for (int i = lane; i < z; i += 64) {
            const int j = zlist[i];
            acc0 += Wr0[j];
            acc1 += Wr1[j];
        }
    } else if (z > ZS_CUT) {
        // Full CSR gather.
        const unsigned s0 = row_start[r0], e0 = row_end[r0];
        for (unsigned k = s0 + (unsigned)lane * 4u; k < e0; k += 256u) {
            float4 w = *(const float4*)(val + k);
            uint2 cc = *(const uint2*)(col + k);
            unsigned c0 = cc.x & 0xffffu, c1 = cc.x >> 16;
            unsigned c2 = cc.y & 0xffffu, c3 = cc.y >> 16;
            if ((bits[c0 >> 5] >> (c0 & 31)) & 1u) acc0 += w.x;
            if ((bits[c1 >> 5] >> (c1 & 31)) & 1u) acc0 += w.y;
            if ((bits[c2 >> 5] >> (c2 & 31)) & 1u) acc0 += w.z;
            if ((bits[c3 >> 5] >> (c3 & 31)) & 1u) acc0 += w.w;
        }
        const unsigned s1 = row_start[r1], e1 = row_end[r1];
        for (unsigned k = s1 + (unsigned)lane * 4u; k < e1; k += 256u) {
            float4 w = *(const float4*)(val + k);
            uint2 cc = *(const uint2*)(col + k);
            unsigned c0 = cc.x & 0xffffu, c1 = cc.x >> 16;
            unsigned c2 = cc.y & 0xffffu, c3 = cc.y >> 16;
            if ((bits[c0 >> 5] >> (c0 & 31)) & 1u) acc1 += w.x;
            if ((bits[c1 >> 5] >> (c1 & 31)) & 1u) acc1 += w.y;
            if ((bits[c2 >> 5] >> (c2 & 31)) & 1u) acc1 += w.z;
            if ((bits[c3 >> 5] >> (c3 & 31)) & 1u) acc1 += w.w;
        }
    }
    #pragma unroll
    for (int off = 1; off < 64; off <<= 1) {
        acc0 += __shfl_xor(acc0, off);
        acc1 += __shfl_xor(acc1, off);
    }

    if (lane == 0) {
        float cur0 = subtractive ? (rowsum[r0] - acc0) : acc0;
        float cur1 = subtractive ? (rowsum[r1] - acc1) : acc1;
        float vn0 = DECAY * v[r0] + cur0;
        float vn1 = DECAY * v[r1] + cur1;
        float f0 = (vn0 >= THRESH) ? 1.0f : 0.0f;
        float f1 = (vn1 >= THRESH) ? 1.0f : 0.0f;
        out[(size_t)t * N_NEURONS + r0] = f0;
        out[(size_t)t * N_NEURONS + r1] = f1;
        out[(size_t)(T_STEPS + t) * N_NEURONS + r0] = vn0;
        out[(size_t)(T_STEPS + t) * N_NEURONS + r1] = vn1;
        v[r0] = (f0 > 0.f) ? 0.f : vn0;
        v[r1] = (f1 > 0.f) ? 0.f : vn1;
        sfire[wave * 2] = f0;
        sfire[wave * 2 + 1] = f1;
    }
    __syncthreads();
    if (tid == 0) {
        unsigned b16 = 0;
        #pragma unroll
        for (int i = 0; i < 16; ++i) b16 |= (sfire[i] > 0.f ? 1u : 0u) << i;
        mout[blockIdx.x] = (unsigned short)b16;
    }
}

// ---- Dense fallback if ws is too small for CSR ----
__global__ __launch_bounds__(256) void step_dense(const float* __restrict__ W,
                                                  const float* __restrict__ fin,
                                                  float* __restrict__ fout,
                                                  float* __restrict__ v,
                                                  float* __restrict__ out_fire,
                                                  float* __restrict__ out_v) {
    __shared__ float fs[N_NEURONS];
    const float4* f4 = (const float4*)fin;
    float4* fs4 = (float4*)fs;
    #pragma unroll
    for (int k = 0; k < N_NEURONS / 4 / 256; ++k)
        fs4[k * 256 + threadIdx.x] = f4[k * 256 + threadIdx.x];
    __syncthreads();

    const int wave = threadIdx.x >> 6, lane = threadIdx.x & 63;
    const int row = blockIdx.x * 4 + wave;
    const float4* Wrow = (const float4*)(W + (size_t)row * N_NEURONS);

    float acc = 0.f;
    #pragma unroll 8
    for (int k = 0; k < N_NEURONS / 4 / 64; ++k) {
        const int idx = k * 64 + lane;
        float4 w = Wrow[idx];
        float4 f = fs4[idx];
        acc += w.x * f.x + w.y * f.y + w.z * f.z + w.w * f.w;
    }
    #pragma unroll
    for (int off = 32; off; off >>= 1) acc += __shfl_down(acc, off);

    if (lane == 0) {
        float vn   = DECAY * v[row] + acc;
        float fire = (vn >= THRESH) ? 1.0f : 0.0f;
        out_fire[row] = fire;
        out_v[row]    = vn;
        fout[row]     = fire;
        v[row]        = (fire > 0.f) ? 0.f : vn;
    }
}

extern "C" void kernel_launch(void* const* d_in, const int* in_sizes, int n_in,
                              void* d_out, int out_size, void* d_ws, size_t ws_size,
                              hipStream_t stream) {
    const float* W  = (const float*)d_in[1];
    const float* f0 = (const float*)d_in[2];
    const float* v0 = (const float*)d_in[3];
    float* out = (float*)d_out;

    char* ws = (char*)d_ws;
    float* v   = (float*)(ws + WS_V_OFF);
    float* fb0 = (float*)(ws + WS_FB0_OFF);
    float* fb1 = (float*)(ws + WS_FB1_OFF);
    unsigned short* m0 = (unsigned short*)(ws + WS_M0_OFF);
    unsigned short* m1 = (unsigned short*)(ws + WS_M1_OFF);
    float* rowsum       = (float*)(ws + WS_RSUM_OFF);
    unsigned* row_start = (unsigned*)(ws + WS_RS_OFF);
    unsigned* row_end   = (unsigned*)(ws + WS_RE_OFF);
    unsigned* counter   = (unsigned*)(ws + WS_CNT_OFF);
    unsigned* done      = (unsigned*)(ws + WS_DONE_OFF);
    int* mrs            = (int*)(ws + WS_MRS_OFF);
    float* val          = (float*)(ws + WS_VAL_OFF);
    unsigned short* col = (unsigned short*)(ws + WS_COL_OFF);

    init_state<<<(N_NEURONS + 255) / 256, 256, 0, stream>>>(
        f0, v0, v, fb0, m0, counter, done, mrs);

    if (ws_size >= WS_REQUIRED) {
        build_csr<<<N_NEURONS / 4, 256, 0, stream>>>(
            W, row_start, row_end, val, col, rowsum, counter, mrs);
        unsigned short* masks[2] = {m0, m1};
        for (int t = 0; t < T_STEPS; ++t) {
            step_adaptive<<<SB_BLOCKS, SB_THREADS, 0, stream>>>(
                row_start, row_end, val, col, rowsum, W,
                (const unsigned*)masks[t & 1], masks[(t + 1) & 1],
                v, out, done, mrs, t);
        }
    } else {
        float* fbufs[2] = {fb0, fb1};
        for (int t = 0; t < T_STEPS; ++t) {
            const float* fin = fbufs[t & 1];
            float* fout      = fbufs[(t + 1) & 1];
            step_dense<<<N_NEURONS / 4, 256, 0, stream>>>(
                W, fin, fout, v,
                out + (size_t)t * N_NEURONS,
                out + (size_t)(T_STEPS + t) * N_NEURONS);
        }
    }
}

// Round 9
// 275.481 us; speedup vs baseline: 12.5465x; 1.2677x over previous
//
#include <hip/hip_runtime.h>
#include <hip/hip_bf16.h>

// SpikingLayer: T=64 sequential LIF steps, cur = W @ f, W ~12% dense.
// Round-9: atomic-free CSR build (same-address atomicAdd-with-return suspected
// to cost ~140us in round 8):
//   count_rows: HBM pass over W -> raw row totals + per-lane u16 offsets
//   scan_rows : 1-block scan of padded totals -> row_start/row_end
//   fill_csr  : L3-hot pass over W, LDS compaction at preloaded offsets,
//               vectorized float4/uint2 dump, per-row rowsum (gather order)
//   reduce_mrs: 1-block min(rowsum)
//   step_adaptive (z = #non-firing from mask popcount):
//     z==0 && minrs>=1 : absorbing -> fill ALL remaining outputs, set done
//     z==0             : cur = rowsum
//     0<z<=256         : cur = rowsum - sum_{j nonfiring} W[row][j]
//     else             : full CSR gather
// Output layout (flat): fires[T][N] at 0, vs[T][N] at T*N.

#define N_NEURONS 8192
#define T_STEPS   64
#define DECAY     0.9f
#define THRESH    1.0f
#define NNZ_CAP   9437184u
#define STAGE_CAP 1536      // max nnz/row ~1175 (mean ~1030) + margin
#define ZS_CUT    256       // dense-column subtract threshold

#define SB_BLOCKS  512      // step grid: 16 rows/block, 8 waves, 2 rows/wave
#define SB_THREADS 512

// ws byte layout:
#define WS_V_OFF    0         // 8192 f32
#define WS_FB0_OFF  32768     // 8192 f32 (dense fallback)
#define WS_FB1_OFF  65536     // 8192 f32 (dense fallback)
#define WS_M0_OFF   98304     // 1024 B mask (bit n = neuron n firing)
#define WS_M1_OFF   99328     // 1024 B mask
#define WS_RSUM_OFF 100352    // 8192 f32 row sums
#define WS_RS_OFF   133120    // 8192 u32 row_start
#define WS_RE_OFF   165888    // 8192 u32 row_end
#define WS_RT_OFF   198656    // 8192 u32 raw row totals
#define WS_LO_OFF   231424    // u16 laneoff[8192][64] = 1 MB
#define WS_DONE_OFF 1280000   // u32 done flag
#define WS_MRS_OFF  1280128   // i32 min-rowsum bits
#define WS_VAL_OFF  1280256   // NNZ_CAP f32 (16B aligned)
#define WS_COL_OFF  (WS_VAL_OFF + (size_t)NNZ_CAP * 4)
#define WS_REQUIRED (WS_COL_OFF + (size_t)NNZ_CAP * 2)

__global__ __launch_bounds__(256) void init_state(const float* __restrict__ f0,
                                                  const float* __restrict__ v0,
                                                  float* __restrict__ v,
                                                  float* __restrict__ fbuf0,
                                                  unsigned short* __restrict__ m0,
                                                  unsigned* __restrict__ done,
                                                  int* __restrict__ mrs) {
    int i = blockIdx.x * 256 + threadIdx.x;
    if (i < N_NEURONS) {
        v[i] = v0[i];
        fbuf0[i] = f0[i];
    }
    if (i < N_NEURONS / 16) {  // mask ushort i covers neurons [16i, 16i+16)
        unsigned b = 0;
        #pragma unroll
        for (int j = 0; j < 16; ++j) b |= (f0[i * 16 + j] != 0.f ? 1u : 0u) << j;
        m0[i] = (unsigned short)b;
    }
    if (i == 0) { *done = 0u; *mrs = 0x7F7FFFFF; }  // FLT_MAX
}

// Pass 1: wave per row, coalesced float4 reads. Writes raw total + per-lane
// exclusive offsets (u16) so fill_csr never recounts. No atomics.
__global__ __launch_bounds__(256) void count_rows(const float* __restrict__ W,
                                                  unsigned* __restrict__ rowtot,
                                                  unsigned short* __restrict__ laneoff) {
    const int wave = threadIdx.x >> 6, lane = threadIdx.x & 63;
    const int row = blockIdx.x * 4 + wave;
    const float4* Wr = (const float4*)(W + (size_t)row * N_NEURONS);

    int c = 0;
    #pragma unroll 8
    for (int k = 0; k < 32; ++k) {
        float4 w = Wr[k * 64 + lane];
        c += (w.x != 0.f) + (w.y != 0.f) + (w.z != 0.f) + (w.w != 0.f);
    }
    int incl = c;
    #pragma unroll
    for (int off = 1; off < 64; off <<= 1) {
        int n = __shfl_up(incl, off);
        if (lane >= off) incl += n;
    }
    if (lane == 63) rowtot[row] = (unsigned)incl;
    laneoff[(size_t)row * 64 + lane] = (unsigned short)(incl - c);
}

// Single block: exclusive scan of 4-padded row counts -> row_start/row_end.
__global__ __launch_bounds__(1024) void scan_rows(const unsigned* __restrict__ rowtot,
                                                  unsigned* __restrict__ row_start,
                                                  unsigned* __restrict__ row_end) {
    __shared__ unsigned part[1024];
    const int t = threadIdx.x;
    unsigned c[8], s = 0;
    #pragma unroll
    for (int i = 0; i < 8; ++i) {
        c[i] = (rowtot[t * 8 + i] + 3u) & ~3u;  // pad to multiple of 4
        s += c[i];
    }
    part[t] = s;
    __syncthreads();
    for (int off = 1; off < 1024; off <<= 1) {
        unsigned add = (t >= off) ? part[t - off] : 0u;
        __syncthreads();
        part[t] += add;
        __syncthreads();
    }
    unsigned base = part[t] - s;  // exclusive
    #pragma unroll
    for (int i = 0; i < 8; ++i) {
        row_start[t * 8 + i] = base;
        base += c[i];
        row_end[t * 8 + i] = base;
    }
}

// Pass 2: wave per row. Coalesced re-read (L3-hot), LDS compaction at the
// preloaded per-lane offsets, vectorized dump, gather-order rowsum.
// No atomics, no __syncthreads (each wave touches only its own LDS row).
__global__ __launch_bounds__(256) void fill_csr(const float* __restrict__ W,
                                                const unsigned* __restrict__ row_start,
                                                const unsigned* __restrict__ row_end,
                                                const unsigned* __restrict__ rowtot,
                                                const unsigned short* __restrict__ laneoff,
                                                float* __restrict__ val,
                                                unsigned short* __restrict__ col,
                                                float* __restrict__ rowsum) {
    __shared__ float          sval[4][STAGE_CAP];
    __shared__ unsigned short scol[4][STAGE_CAP];

    const int wave = threadIdx.x >> 6, lane = threadIdx.x & 63;
    const int row = blockIdx.x * 4 + wave;
    const float4* Wr = (const float4*)(W + (size_t)row * N_NEURONS);

    const unsigned gbase  = row_start[row];
    const unsigned padded = row_end[row] - gbase;
    const unsigned total  = rowtot[row];
    unsigned p = laneoff[(size_t)row * 64 + lane];

    #pragma unroll 4
    for (int k = 0; k < 32; ++k) {
        const int idx = k * 64 + lane;
        float4 w = Wr[idx];
        const int c0 = idx * 4;
        if (w.x != 0.f) { sval[wave][p] = w.x; scol[wave][p] = (unsigned short)c0;       ++p; }
        if (w.y != 0.f) { sval[wave][p] = w.y; scol[wave][p] = (unsigned short)(c0 + 1); ++p; }
        if (w.z != 0.f) { sval[wave][p] = w.z; scol[wave][p] = (unsigned short)(c0 + 2); ++p; }
        if (w.w != 0.f) { sval[wave][p] = w.w; scol[wave][p] = (unsigned short)(c0 + 3); ++p; }
    }
    if (lane < (int)(padded - total)) {  // zero pads
        sval[wave][total + lane] = 0.f;
        scol[wave][total + lane] = 0;
    }
    // Intra-wave LDS write->read ordering is handled by compiler waitcnts.

    // Vectorized dump: ds_read_b128 + 16B/8B coalesced global stores.
    const float4* sv4 = (const float4*)(&sval[wave][0]);   // 16B-aligned base
    float4* v4 = (float4*)(val + gbase);                   // gbase % 4 == 0
    for (unsigned i = lane; i < padded / 4u; i += 64) v4[i] = sv4[i];
    const uint2* sc4 = (const uint2*)(&scol[wave][0]);     // 8B-aligned base
    uint2* c4 = (uint2*)(col + gbase);
    for (unsigned i = lane; i < padded / 4u; i += 64) c4[i] = sc4[i];

    // rowsum in the step kernel's exact gather order.
    float rsum = 0.f;
    for (unsigned i = (unsigned)lane * 4u; i < padded; i += 256u) {
        rsum += sval[wave][i];
        rsum += sval[wave][i + 1];
        rsum += sval[wave][i + 2];
        rsum += sval[wave][i + 3];
    }
    #pragma unroll
    for (int off = 1; off < 64; off <<= 1) rsum += __shfl_xor(rsum, off);
    if (lane == 0) rowsum[row] = rsum;
}

// Single block: min over rowsum[8192] -> mrs (int-ordered positive floats).
__global__ __launch_bounds__(1024) void reduce_mrs(const float* __restrict__ rowsum,
                                                   int* __restrict__ mrs) {
    __shared__ float sm[16];
    const int t = threadIdx.x, wave = t >> 6, lane = t & 63;
    float m = 3.4e38f;
    #pragma unroll
    for (int i = 0; i < 8; ++i) m = fminf(m, rowsum[i * 1024 + t]);
    #pragma unroll
    for (int off = 1; off < 64; off <<= 1) m = fminf(m, __shfl_xor(m, off));
    if (lane == 0) sm[wave] = m;
    __syncthreads();
    if (t == 0) {
        #pragma unroll
        for (int i = 1; i < 16; ++i) m = fminf(sm[0], sm[i]), sm[0] = m;
        *mrs = __float_as_int(sm[0]);
    }
}

// Adaptive step. 512 blocks x 512 threads; block owns 16 rows; wave owns 2.
__global__ __launch_bounds__(SB_THREADS) void step_adaptive(
        const unsigned* __restrict__ row_start, const unsigned* __restrict__ row_end,
        const float* __restrict__ val, const unsigned short* __restrict__ col,
        const float* __restrict__ rowsum, const float* __restrict__ W,
        const unsigned* __restrict__ min_mask, unsigned short* __restrict__ mout,
        float* __restrict__ v, float* __restrict__ out,
        unsigned* __restrict__ done, const int* __restrict__ mrs, int t) {
    if (*done) return;  // absorbing state already filled

    __shared__ unsigned bits[N_NEURONS / 32];  // 1 KB
    __shared__ float sfire[16];
    __shared__ int kcnt, wpart[4];
    __shared__ unsigned short zlist[ZS_CUT];

    const int tid = threadIdx.x, wave = tid >> 6, lane = tid & 63;
    const int bb = blockIdx.x * 16;
    const int r0 = bb + wave * 2, r1 = r0 + 1;

    if (tid == 0) kcnt = 0;
    __syncthreads();
    if (tid < 256) {
        unsigned w = min_mask[tid];
        bits[tid] = w;
        atomicAdd(&kcnt, __popc(w));
    }
    __syncthreads();
    const int z = N_NEURONS - kcnt;
    const float minrs = __int_as_float(*mrs);

    if (z == 0 && minrs >= THRESH) {
        // Absorbing: all rows fired last step => v==0 everywhere. Every
        // remaining step: fire=1, v_pre=rowsum (bit-exact), v resets to 0.
        if (tid < 16) {
            const float rs = rowsum[bb + tid];
            for (int tt = t; tt < T_STEPS; ++tt) {
                out[(size_t)tt * N_NEURONS + bb + tid] = 1.0f;
                out[(size_t)(T_STEPS + tt) * N_NEURONS + bb + tid] = rs;
            }
        }
        __syncthreads();
        if (tid == 0) *done = 1u;
        return;
    }

    float acc0 = 0.f, acc1 = 0.f;
    const bool subtractive = (z <= ZS_CUT);  // includes z==0 (acc stays 0)

    if (z > 0 && z <= ZS_CUT) {
        // Deterministic ascending zero-list via block scan over 256 words.
        int zc = 0, word = 0, incl = 0;
        if (tid < 256) {
            word = (int)bits[tid];
            zc = 32 - __popc((unsigned)word);
            incl = zc;
            #pragma unroll
            for (int off = 1; off < 64; off <<= 1) {
                int n = __shfl_up(incl, off);
                if (lane >= off) incl += n;
            }
            if (lane == 63) wpart[wave] = incl;
        }
        __syncthreads();
        if (tid < 256) {
            int base = 0;
            for (int wv = 0; wv < wave; ++wv) base += wpart[wv];
            int off = base + incl - zc;
            for (int b = 0; b < 32; ++b)
                if (!((word >> b) & 1)) zlist[off++] = (unsigned short)(tid * 32 + b);
        }
        __syncthreads();
        // Dense-column subtraction, ascending j per lane (deterministic).
        const float* Wr0 = W + (size_t)r0 * N_NEURONS;
        const float* Wr1 = W + (size_t)r1 * N_NEURONS;
        for (int i = lane; i < z; i += 64) {
            const int j = zlist[i];
            acc0 += Wr0[j];
            acc1 += Wr1[j];
        }
    } else if (z > ZS_CUT) {
        // Full CSR gather.
        const unsigned s0 = row_start[r0], e0 = row_end[r0];
        for (unsigned k = s0 + (unsigned)lane * 4u; k < e0; k += 256u) {
            float4 w = *(const float4*)(val + k);
            uint2 cc = *(const uint2*)(col + k);
            unsigned c0 = cc.x & 0xffffu, c1 = cc.x >> 16;
            unsigned c2 = cc.y & 0xffffu, c3 = cc.y >> 16;
            if ((bits[c0 >> 5] >> (c0 & 31)) & 1u) acc0 += w.x;
            if ((bits[c1 >> 5] >> (c1 & 31)) & 1u) acc0 += w.y;
            if ((bits[c2 >> 5] >> (c2 & 31)) & 1u) acc0 += w.z;
            if ((bits[c3 >> 5] >> (c3 & 31)) & 1u) acc0 += w.w;
        }
        const unsigned s1 = row_start[r1], e1 = row_end[r1];
        for (unsigned k = s1 + (unsigned)lane * 4u; k < e1; k += 256u) {
            float4 w = *(const float4*)(val + k);
            uint2 cc = *(const uint2*)(col + k);
            unsigned c0 = cc.x & 0xffffu, c1 = cc.x >> 16;
            unsigned c2 = cc.y & 0xffffu, c3 = cc.y >> 16;
            if ((bits[c0 >> 5] >> (c0 & 31)) & 1u) acc1 += w.x;
            if ((bits[c1 >> 5] >> (c1 & 31)) & 1u) acc1 += w.y;
            if ((bits[c2 >> 5] >> (c2 & 31)) & 1u) acc1 += w.z;
            if ((bits[c3 >> 5] >> (c3 & 31)) & 1u) acc1 += w.w;
        }
    }
    #pragma unroll
    for (int off = 1; off < 64; off <<= 1) {
        acc0 += __shfl_xor(acc0, off);
        acc1 += __shfl_xor(acc1, off);
    }

    if (lane == 0) {
        float cur0 = subtractive ? (rowsum[r0] - acc0) : acc0;
        float cur1 = subtractive ? (rowsum[r1] - acc1) : acc1;
        float vn0 = DECAY * v[r0] + cur0;
        float vn1 = DECAY * v[r1] + cur1;
        float f0 = (vn0 >= THRESH) ? 1.0f : 0.0f;
        float f1 = (vn1 >= THRESH) ? 1.0f : 0.0f;
        out[(size_t)t * N_NEURONS + r0] = f0;
        out[(size_t)t * N_NEURONS + r1] = f1;
        out[(size_t)(T_STEPS + t) * N_NEURONS + r0] = vn0;
        out[(size_t)(T_STEPS + t) * N_NEURONS + r1] = vn1;
        v[r0] = (f0 > 0.f) ? 0.f : vn0;
        v[r1] = (f1 > 0.f) ? 0.f : vn1;
        sfire[wave * 2] = f0;
        sfire[wave * 2 + 1] = f1;
    }
    __syncthreads();
    if (tid == 0) {
        unsigned b16 = 0;
        #pragma unroll
        for (int i = 0; i < 16; ++i) b16 |= (sfire[i] > 0.f ? 1u : 0u) << i;
        mout[blockIdx.x] = (unsigned short)b16;
    }
}

// ---- Dense fallback if ws is too small for CSR ----
__global__ __launch_bounds__(256) void step_dense(const float* __restrict__ W,
                                                  const float* __restrict__ fin,
                                                  float* __restrict__ fout,
                                                  float* __restrict__ v,
                                                  float* __restrict__ out_fire,
                                                  float* __restrict__ out_v) {
    __shared__ float fs[N_NEURONS];
    const float4* f4 = (const float4*)fin;
    float4* fs4 = (float4*)fs;
    #pragma unroll
    for (int k = 0; k < N_NEURONS / 4 / 256; ++k)
        fs4[k * 256 + threadIdx.x] = f4[k * 256 + threadIdx.x];
    __syncthreads();

    const int wave = threadIdx.x >> 6, lane = threadIdx.x & 63;
    const int row = blockIdx.x * 4 + wave;
    const float4* Wrow = (const float4*)(W + (size_t)row * N_NEURONS);

    float acc = 0.f;
    #pragma unroll 8
    for (int k = 0; k < N_NEURONS / 4 / 64; ++k) {
        const int idx = k * 64 + lane;
        float4 w = Wrow[idx];
        float4 f = fs4[idx];
        acc += w.x * f.x + w.y * f.y + w.z * f.z + w.w * f.w;
    }
    #pragma unroll
    for (int off = 32; off; off >>= 1) acc += __shfl_down(acc, off);

    if (lane == 0) {
        float vn   = DECAY * v[row] + acc;
        float fire = (vn >= THRESH) ? 1.0f : 0.0f;
        out_fire[row] = fire;
        out_v[row]    = vn;
        fout[row]     = fire;
        v[row]        = (fire > 0.f) ? 0.f : vn;
    }
}

extern "C" void kernel_launch(void* const* d_in, const int* in_sizes, int n_in,
                              void* d_out, int out_size, void* d_ws, size_t ws_size,
                              hipStream_t stream) {
    const float* W  = (const float*)d_in[1];
    const float* f0 = (const float*)d_in[2];
    const float* v0 = (const float*)d_in[3];
    float* out = (float*)d_out;

    char* ws = (char*)d_ws;
    float* v   = (float*)(ws + WS_V_OFF);
    float* fb0 = (float*)(ws + WS_FB0_OFF);
    float* fb1 = (float*)(ws + WS_FB1_OFF);
    unsigned short* m0 = (unsigned short*)(ws + WS_M0_OFF);
    unsigned short* m1 = (unsigned short*)(ws + WS_M1_OFF);
    float* rowsum          = (float*)(ws + WS_RSUM_OFF);
    unsigned* row_start    = (unsigned*)(ws + WS_RS_OFF);
    unsigned* row_end      = (unsigned*)(ws + WS_RE_OFF);
    unsigned* rowtot       = (unsigned*)(ws + WS_RT_OFF);
    unsigned short* laneoff = (unsigned short*)(ws + WS_LO_OFF);
    unsigned* done         = (unsigned*)(ws + WS_DONE_OFF);
    int* mrs               = (int*)(ws + WS_MRS_OFF);
    float* val             = (float*)(ws + WS_VAL_OFF);
    unsigned short* col    = (unsigned short*)(ws + WS_COL_OFF);

    init_state<<<(N_NEURONS + 255) / 256, 256, 0, stream>>>(
        f0, v0, v, fb0, m0, done, mrs);

    if (ws_size >= WS_REQUIRED) {
        count_rows<<<N_NEURONS / 4, 256, 0, stream>>>(W, rowtot, laneoff);
        scan_rows<<<1, 1024, 0, stream>>>(rowtot, row_start, row_end);
        fill_csr<<<N_NEURONS / 4, 256, 0, stream>>>(
            W, row_start, row_end, rowtot, laneoff, val, col, rowsum);
        reduce_mrs<<<1, 1024, 0, stream>>>(rowsum, mrs);
        unsigned short* masks[2] = {m0, m1};
        for (int t = 0; t < T_STEPS; ++t) {
            step_adaptive<<<SB_BLOCKS, SB_THREADS, 0, stream>>>(
                row_start, row_end, val, col, rowsum, W,
                (const unsigned*)masks[t & 1], masks[(t + 1) & 1],
                v, out, done, mrs, t);
        }
    } else {
        float* fbufs[2] = {fb0, fb1};
        for (int t = 0; t < T_STEPS; ++t) {
            const float* fin = fbufs[t & 1];
            float* fout      = fbufs[(t + 1) & 1];
            step_dense<<<N_NEURONS / 4, 256, 0, stream>>>(
                W, fin, fout, v,
                out + (size_t)t * N_NEURONS,
                out + (size_t)(T_STEPS + t) * N_NEURONS);
        }
    }
}

// Round 10
// 191.004 us; speedup vs baseline: 18.0956x; 1.4423x over previous
//
#include <hip/hip_runtime.h>
#include <hip/hip_bf16.h>

// SpikingLayer: T=64 sequential LIF steps, cur = W @ f, W ~12% dense.
// Round-10:
//   fill_ell : ONE W pass -> ELLPACK (fixed 1280-entry slot/row, no atomics,
//              no scan). Falls back to round-9 CSR build if ws too small.
//   steps    : only 16 step_adaptive launches (absorption at t~4 analytically
//              and empirically) + step_tail (1 block) that finishes t=16..63
//              correctly if absorption hasn't happened (never for this input,
//              ~2us early-exit when it has).
//   step_adaptive modes (z = #non-firing from mask popcount):
//     z==0 && minrs>=1 : absorbing -> fill ALL remaining outputs, set done
//     z==0             : cur = rowsum
//     0<z<=256         : cur = rowsum - sum_{j nonfiring} W[row][j]
//     else             : full gather
// Output layout (flat): fires[T][N] at 0, vs[T][N] at T*N.

#define N_NEURONS 8192
#define T_STEPS   64
#define DECAY     0.9f
#define THRESH    1.0f
#define ELL_SLOT  1280      // max nnz/row ~1180 (mean ~1030, std ~30)
#define STAGE_CAP 1280
#define NNZ_CAP   9437184u  // CSR fallback cap
#define ZS_CUT    256
#define K_STEPS   16        // individually-launched steps before the tail

#define SB_BLOCKS  512      // step grid: 16 rows/block, 8 waves, 2 rows/wave
#define SB_THREADS 512

// ws byte layout (shared header for both paths):
#define WS_V_OFF    0         // 8192 f32
#define WS_FB0_OFF  32768     // 8192 f32 (dense fallback)
#define WS_FB1_OFF  65536     // 8192 f32 (dense fallback)
#define WS_M0_OFF   98304     // 1024 B mask (bit n = neuron n firing)
#define WS_M1_OFF   99328     // 1024 B mask
#define WS_RSUM_OFF 100352    // 8192 f32 row sums
#define WS_RS_OFF   133120    // 8192 u32 row_start
#define WS_RE_OFF   165888    // 8192 u32 row_end
#define WS_RT_OFF   198656    // 8192 u32 raw row totals (CSR path)
#define WS_LO_OFF   231424    // u16 laneoff[8192][64] = 1 MB (CSR path)
#define WS_DONE_OFF 1280000   // u32 done flag
#define WS_MRS_OFF  1280128   // i32 min-rowsum bits
#define WS_VAL_OFF  1280256   // values (16B aligned)
// ELL: val = 8192*1280 f32, col = 8192*1280 u16
#define WS_ELL_COL_OFF (WS_VAL_OFF + (size_t)N_NEURONS * ELL_SLOT * 4)
#define WS_ELL_REQUIRED (WS_ELL_COL_OFF + (size_t)N_NEURONS * ELL_SLOT * 2)
// CSR: val = NNZ_CAP f32, col = NNZ_CAP u16
#define WS_CSR_COL_OFF (WS_VAL_OFF + (size_t)NNZ_CAP * 4)
#define WS_CSR_REQUIRED (WS_CSR_COL_OFF + (size_t)NNZ_CAP * 2)

__global__ __launch_bounds__(256) void init_state(const float* __restrict__ f0,
                                                  const float* __restrict__ v0,
                                                  float* __restrict__ v,
                                                  float* __restrict__ fbuf0,
                                                  unsigned short* __restrict__ m0,
                                                  unsigned* __restrict__ done,
                                                  int* __restrict__ mrs) {
    int i = blockIdx.x * 256 + threadIdx.x;
    if (i < N_NEURONS) {
        v[i] = v0[i];
        fbuf0[i] = f0[i];
    }
    if (i < N_NEURONS / 16) {
        unsigned b = 0;
        #pragma unroll
        for (int j = 0; j < 16; ++j) b |= (f0[i * 16 + j] != 0.f ? 1u : 0u) << j;
        m0[i] = (unsigned short)b;
    }
    if (i == 0) { *done = 0u; *mrs = 0x7F7FFFFF; }  // FLT_MAX
}

// ---- ELL build: ONE pass over W. Wave per row; in-wave count+scan; LDS
// compaction at per-lane offsets; vectorized dump to the row's fixed slot. ----
__global__ __launch_bounds__(256) void fill_ell(const float* __restrict__ W,
                                                unsigned* __restrict__ row_start,
                                                unsigned* __restrict__ row_end,
                                                float* __restrict__ val,
                                                unsigned short* __restrict__ col,
                                                float* __restrict__ rowsum) {
    __shared__ float          sval[4][STAGE_CAP];
    __shared__ unsigned short scol[4][STAGE_CAP];

    const int wave = threadIdx.x >> 6, lane = threadIdx.x & 63;
    const int row = blockIdx.x * 4 + wave;
    const float4* Wr = (const float4*)(W + (size_t)row * N_NEURONS);

    // count (HBM pass)
    int c = 0;
    #pragma unroll 8
    for (int k = 0; k < 32; ++k) {
        float4 w = Wr[k * 64 + lane];
        c += (w.x != 0.f) + (w.y != 0.f) + (w.z != 0.f) + (w.w != 0.f);
    }
    int incl = c;
    #pragma unroll
    for (int off = 1; off < 64; off <<= 1) {
        int n = __shfl_up(incl, off);
        if (lane >= off) incl += n;
    }
    const unsigned total  = (unsigned)__shfl(incl, 63);
    const unsigned padded = (total + 3u) & ~3u;
    const unsigned gbase  = (unsigned)row * ELL_SLOT;
    if (lane == 0) { row_start[row] = gbase; row_end[row] = gbase + padded; }

    // re-read (L1/L2-hot) + compact into LDS at per-lane run [incl-c, incl)
    unsigned p = (unsigned)(incl - c);
    #pragma unroll 4
    for (int k = 0; k < 32; ++k) {
        const int idx = k * 64 + lane;
        float4 w = Wr[idx];
        const int c0 = idx * 4;
        if (w.x != 0.f) { sval[wave][p] = w.x; scol[wave][p] = (unsigned short)c0;       ++p; }
        if (w.y != 0.f) { sval[wave][p] = w.y; scol[wave][p] = (unsigned short)(c0 + 1); ++p; }
        if (w.z != 0.f) { sval[wave][p] = w.z; scol[wave][p] = (unsigned short)(c0 + 2); ++p; }
        if (w.w != 0.f) { sval[wave][p] = w.w; scol[wave][p] = (unsigned short)(c0 + 3); ++p; }
    }
    if (lane < (int)(padded - total)) {  // zero pads
        sval[wave][total + lane] = 0.f;
        scol[wave][total + lane] = 0;
    }

    // vectorized dump (each wave owns its LDS row; intra-wave ordering by HW)
    const float4* sv4 = (const float4*)(&sval[wave][0]);
    float4* v4 = (float4*)(val + gbase);                // gbase*4 % 16 == 0
    for (unsigned i = lane; i < padded / 4u; i += 64) v4[i] = sv4[i];
    const uint2* sc4 = (const uint2*)(&scol[wave][0]);
    uint2* c4 = (uint2*)(col + gbase);                  // gbase*2 % 8 == 0
    for (unsigned i = lane; i < padded / 4u; i += 64) c4[i] = sc4[i];

    // rowsum in the step kernel's exact gather order
    float rsum = 0.f;
    for (unsigned i = (unsigned)lane * 4u; i < padded; i += 256u) {
        rsum += sval[wave][i];
        rsum += sval[wave][i + 1];
        rsum += sval[wave][i + 2];
        rsum += sval[wave][i + 3];
    }
    #pragma unroll
    for (int off = 1; off < 64; off <<= 1) rsum += __shfl_xor(rsum, off);
    if (lane == 0) rowsum[row] = rsum;
}

// ---- CSR fallback build (round-9, atomic-free 3-kernel pipeline) ----
__global__ __launch_bounds__(256) void count_rows(const float* __restrict__ W,
                                                  unsigned* __restrict__ rowtot,
                                                  unsigned short* __restrict__ laneoff) {
    const int wave = threadIdx.x >> 6, lane = threadIdx.x & 63;
    const int row = blockIdx.x * 4 + wave;
    const float4* Wr = (const float4*)(W + (size_t)row * N_NEURONS);
    int c = 0;
    #pragma unroll 8
    for (int k = 0; k < 32; ++k) {
        float4 w = Wr[k * 64 + lane];
        c += (w.x != 0.f) + (w.y != 0.f) + (w.z != 0.f) + (w.w != 0.f);
    }
    int incl = c;
    #pragma unroll
    for (int off = 1; off < 64; off <<= 1) {
        int n = __shfl_up(incl, off);
        if (lane >= off) incl += n;
    }
    if (lane == 63) rowtot[row] = (unsigned)incl;
    laneoff[(size_t)row * 64 + lane] = (unsigned short)(incl - c);
}

__global__ __launch_bounds__(1024) void scan_rows(const unsigned* __restrict__ rowtot,
                                                  unsigned* __restrict__ row_start,
                                                  unsigned* __restrict__ row_end) {
    __shared__ unsigned part[1024];
    const int t = threadIdx.x;
    unsigned c[8], s = 0;
    #pragma unroll
    for (int i = 0; i < 8; ++i) {
        c[i] = (rowtot[t * 8 + i] + 3u) & ~3u;
        s += c[i];
    }
    part[t] = s;
    __syncthreads();
    for (int off = 1; off < 1024; off <<= 1) {
        unsigned add = (t >= off) ? part[t - off] : 0u;
        __syncthreads();
        part[t] += add;
        __syncthreads();
    }
    unsigned base = part[t] - s;
    #pragma unroll
    for (int i = 0; i < 8; ++i) {
        row_start[t * 8 + i] = base;
        base += c[i];
        row_end[t * 8 + i] = base;
    }
}

__global__ __launch_bounds__(256) void fill_csr(const float* __restrict__ W,
                                                const unsigned* __restrict__ row_start,
                                                const unsigned* __restrict__ row_end,
                                                const unsigned* __restrict__ rowtot,
                                                const unsigned short* __restrict__ laneoff,
                                                float* __restrict__ val,
                                                unsigned short* __restrict__ col,
                                                float* __restrict__ rowsum) {
    __shared__ float          sval[4][STAGE_CAP];
    __shared__ unsigned short scol[4][STAGE_CAP];

    const int wave = threadIdx.x >> 6, lane = threadIdx.x & 63;
    const int row = blockIdx.x * 4 + wave;
    const float4* Wr = (const float4*)(W + (size_t)row * N_NEURONS);

    const unsigned gbase  = row_start[row];
    const unsigned padded = row_end[row] - gbase;
    const unsigned total  = rowtot[row];
    unsigned p = laneoff[(size_t)row * 64 + lane];

    #pragma unroll 4
    for (int k = 0; k < 32; ++k) {
        const int idx = k * 64 + lane;
        float4 w = Wr[idx];
        const int c0 = idx * 4;
        if (w.x != 0.f) { sval[wave][p] = w.x; scol[wave][p] = (unsigned short)c0;       ++p; }
        if (w.y != 0.f) { sval[wave][p] = w.y; scol[wave][p] = (unsigned short)(c0 + 1); ++p; }
        if (w.z != 0.f) { sval[wave][p] = w.z; scol[wave][p] = (unsigned short)(c0 + 2); ++p; }
        if (w.w != 0.f) { sval[wave][p] = w.w; scol[wave][p] = (unsigned short)(c0 + 3); ++p; }
    }
    if (lane < (int)(padded - total)) {
        sval[wave][total + lane] = 0.f;
        scol[wave][total + lane] = 0;
    }

    const float4* sv4 = (const float4*)(&sval[wave][0]);
    float4* v4 = (float4*)(val + gbase);
    for (unsigned i = lane; i < padded / 4u; i += 64) v4[i] = sv4[i];
    const uint2* sc4 = (const uint2*)(&scol[wave][0]);
    uint2* c4 = (uint2*)(col + gbase);
    for (unsigned i = lane; i < padded / 4u; i += 64) c4[i] = sc4[i];

    float rsum = 0.f;
    for (unsigned i = (unsigned)lane * 4u; i < padded; i += 256u) {
        rsum += sval[wave][i];
        rsum += sval[wave][i + 1];
        rsum += sval[wave][i + 2];
        rsum += sval[wave][i + 3];
    }
    #pragma unroll
    for (int off = 1; off < 64; off <<= 1) rsum += __shfl_xor(rsum, off);
    if (lane == 0) rowsum[row] = rsum;
}

__global__ __launch_bounds__(1024) void reduce_mrs(const float* __restrict__ rowsum,
                                                   int* __restrict__ mrs) {
    __shared__ float sm[16];
    const int t = threadIdx.x, wave = t >> 6, lane = t & 63;
    float m = 3.4e38f;
    #pragma unroll
    for (int i = 0; i < 8; ++i) m = fminf(m, rowsum[i * 1024 + t]);
    #pragma unroll
    for (int off = 1; off < 64; off <<= 1) m = fminf(m, __shfl_xor(m, off));
    if (lane == 0) sm[wave] = m;
    __syncthreads();
    if (t == 0) {
        #pragma unroll
        for (int i = 1; i < 16; ++i) m = fminf(m, sm[i]);
        *mrs = __float_as_int(m);
    }
}

// Adaptive step. 512 blocks x 512 threads; block owns 16 rows; wave owns 2.
__global__ __launch_bounds__(SB_THREADS) void step_adaptive(
        const unsigned* __restrict__ row_start, const unsigned* __restrict__ row_end,
        const float* __restrict__ val, const unsigned short* __restrict__ col,
        const float* __restrict__ rowsum, const float* __restrict__ W,
        const unsigned* __restrict__ min_mask, unsigned short* __restrict__ mout,
        float* __restrict__ v, float* __restrict__ out,
        unsigned* __restrict__ done, const int* __restrict__ mrs, int t) {
    if (*done) return;

    __shared__ unsigned bits[N_NEURONS / 32];
    __shared__ float sfire[16];
    __shared__ int kcnt, wpart[4];
    __shared__ unsigned short zlist[ZS_CUT];

    const int tid = threadIdx.x, wave = tid >> 6, lane = tid & 63;
    const int bb = blockIdx.x * 16;
    const int r0 = bb + wave * 2, r1 = r0 + 1;

    if (tid == 0) kcnt = 0;
    __syncthreads();
    if (tid < 256) {
        unsigned w = min_mask[tid];
        bits[tid] = w;
        atomicAdd(&kcnt, __popc(w));
    }
    __syncthreads();
    const int z = N_NEURONS - kcnt;
    const float minrs = __int_as_float(*mrs);

    if (z == 0 && minrs >= THRESH) {
        if (tid < 16) {
            const float rs = rowsum[bb + tid];
            for (int tt = t; tt < T_STEPS; ++tt) {
                out[(size_t)tt * N_NEURONS + bb + tid] = 1.0f;
                out[(size_t)(T_STEPS + tt) * N_NEURONS + bb + tid] = rs;
            }
        }
        __syncthreads();
        if (tid == 0) *done = 1u;
        return;
    }

    float acc0 = 0.f, acc1 = 0.f;
    const bool subtractive = (z <= ZS_CUT);

    if (z > 0 && z <= ZS_CUT) {
        int zc = 0, word = 0, incl = 0;
        if (tid < 256) {
            word = (int)bits[tid];
            zc = 32 - __popc((unsigned)word);
            incl = zc;
            #pragma unroll
            for (int off = 1; off < 64; off <<= 1) {
                int n = __shfl_up(incl, off);
                if (lane >= off) incl += n;
            }
            if (lane == 63) wpart[wave] = incl;
        }
        __syncthreads();
        if (tid < 256) {
            int base = 0;
            for (int wv = 0; wv < wave; ++wv) base += wpart[wv];
            int off = base + incl - zc;
            for (int b = 0; b < 32; ++b)
                if (!((word >> b) & 1)) zlist[off++] = (unsigned short)(tid * 32 + b);
        }
        __syncthreads();
        const float* Wr0 = W + (size_t)r0 * N_NEURONS;
        const float* Wr1 = W + (size_t)r1 * N_NEURONS;
        for (int i = lane; i < z; i += 64) {
            const int j = zlist[i];
            acc0 += Wr0[j];
            acc1 += Wr1[j];
        }
    } else if (z > ZS_CUT) {
        const unsigned s0 = row_start[r0], e0 = row_end[r0];
        for (unsigned k = s0 + (unsigned)lane * 4u; k < e0; k += 256u) {
            float4 w = *(const float4*)(val + k);
            uint2 cc = *(const uint2*)(col + k);
            unsigned c0 = cc.x & 0xffffu, c1 = cc.x >> 16;
            unsigned c2 = cc.y & 0xffffu, c3 = cc.y >> 16;
            if ((bits[c0 >> 5] >> (c0 & 31)) & 1u) acc0 += w.x;
            if ((bits[c1 >> 5] >> (c1 & 31)) & 1u) acc0 += w.y;
            if ((bits[c2 >> 5] >> (c2 & 31)) & 1u) acc0 += w.z;
            if ((bits[c3 >> 5] >> (c3 & 31)) & 1u) acc0 += w.w;
        }
        const unsigned s1 = row_start[r1], e1 = row_end[r1];
        for (unsigned k = s1 + (unsigned)lane * 4u; k < e1; k += 256u) {
            float4 w = *(const float4*)(val + k);
            uint2 cc = *(const uint2*)(col + k);
            unsigned c0 = cc.x & 0xffffu, c1 = cc.x >> 16;
            unsigned c2 = cc.y & 0xffffu, c3 = cc.y >> 16;
            if ((bits[c0 >> 5] >> (c0 & 31)) & 1u) acc1 += w.x;
            if ((bits[c1 >> 5] >> (c1 & 31)) & 1u) acc1 += w.y;
            if ((bits[c2 >> 5] >> (c2 & 31)) & 1u) acc1 += w.z;
            if ((bits[c3 >> 5] >> (c3 & 31)) & 1u) acc1 += w.w;
        }
    }
    #pragma unroll
    for (int off = 1; off < 64; off <<= 1) {
        acc0 += __shfl_xor(acc0, off);
        acc1 += __shfl_xor(acc1, off);
    }

    if (lane == 0) {
        float cur0 = subtractive ? (rowsum[r0] - acc0) : acc0;
        float cur1 = subtractive ? (rowsum[r1] - acc1) : acc1;
        float vn0 = DECAY * v[r0] + cur0;
        float vn1 = DECAY * v[r1] + cur1;
        float f0 = (vn0 >= THRESH) ? 1.0f : 0.0f;
        float f1 = (vn1 >= THRESH) ? 1.0f : 0.0f;
        out[(size_t)t * N_NEURONS + r0] = f0;
        out[(size_t)t * N_NEURONS + r1] = f1;
        out[(size_t)(T_STEPS + t) * N_NEURONS + r0] = vn0;
        out[(size_t)(T_STEPS + t) * N_NEURONS + r1] = vn1;
        v[r0] = (f0 > 0.f) ? 0.f : vn0;
        v[r1] = (f1 > 0.f) ? 0.f : vn1;
        sfire[wave * 2] = f0;
        sfire[wave * 2 + 1] = f1;
    }
    __syncthreads();
    if (tid == 0) {
        unsigned b16 = 0;
        #pragma unroll
        for (int i = 0; i < 16; ++i) b16 |= (sfire[i] > 0.f ? 1u : 0u) << i;
        mout[blockIdx.x] = (unsigned short)b16;
    }
}

// Tail: ONE block finishes steps K_STEPS..63 if absorption hasn't happened.
// Early-exits (~2us) when done is set. Mask lives in LDS; per-step
// __syncthreads; no grid sync needed. Slow if ever truly exercised -- it
// never is for this input (absorption at t~4), but keeps K_STEPS=16 safe.
__global__ __launch_bounds__(1024) void step_tail(
        const unsigned* __restrict__ row_start, const unsigned* __restrict__ row_end,
        const float* __restrict__ val, const unsigned short* __restrict__ col,
        const float* __restrict__ rowsum, const float* __restrict__ W,
        const unsigned* __restrict__ mask_in,  // masks[K_STEPS & 1]
        float* __restrict__ v, float* __restrict__ out,
        const unsigned* __restrict__ done, const int* __restrict__ mrs) {
    if (*done) return;

    __shared__ unsigned bits[256], newbits[256];
    __shared__ int kcnt, wpart[4];
    __shared__ unsigned short zlist[ZS_CUT];

    const int tid = threadIdx.x, wave = tid >> 6, lane = tid & 63;
    const float minrs = __int_as_float(*mrs);

    if (tid < 256) bits[tid] = mask_in[tid];
    __syncthreads();

    for (int t = K_STEPS; t < T_STEPS; ++t) {
        if (tid == 0) kcnt = 0;
        __syncthreads();
        if (tid < 256) atomicAdd(&kcnt, __popc(bits[tid]));
        __syncthreads();
        const int z = N_NEURONS - kcnt;

        if (z == 0 && minrs >= THRESH) {
            for (int tt = t; tt < T_STEPS; ++tt)
                for (int i = tid; i < N_NEURONS; i += 1024) {
                    out[(size_t)tt * N_NEURONS + i] = 1.0f;
                    out[(size_t)(T_STEPS + tt) * N_NEURONS + i] = rowsum[i];
                }
            return;
        }

        const bool subtractive = (z <= ZS_CUT);
        if (z > 0 && z <= ZS_CUT) {
            int zc = 0, word = 0, incl = 0;
            if (tid < 256) {
                word = (int)bits[tid];
                zc = 32 - __popc((unsigned)word);
                incl = zc;
                #pragma unroll
                for (int off = 1; off < 64; off <<= 1) {
                    int n = __shfl_up(incl, off);
                    if (lane >= off) incl += n;
                }
                if (lane == 63) wpart[wave] = incl;
            }
            __syncthreads();
            if (tid < 256) {
                int base = 0;
                for (int wv = 0; wv < wave; ++wv) base += wpart[wv];
                int off = base + incl - zc;
                for (int b = 0; b < 32; ++b)
                    if (!((word >> b) & 1)) zlist[off++] = (unsigned short)(tid * 32 + b);
            }
            __syncthreads();
        }
        if (tid < 256) newbits[tid] = 0;
        __syncthreads();

        // 16 waves sweep all 8192 rows
        for (int r = wave; r < N_NEURONS; r += 16) {
            float acc = 0.f;
            if (z > 0 && z <= ZS_CUT) {
                const float* Wr = W + (size_t)r * N_NEURONS;
                for (int i = lane; i < z; i += 64) acc += Wr[zlist[i]];
            } else if (z > ZS_CUT) {
                const unsigned s = row_start[r], e = row_end[r];
                for (unsigned k = s + (unsigned)lane * 4u; k < e; k += 256u) {
                    float4 w = *(const float4*)(val + k);
                    uint2 cc = *(const uint2*)(col + k);
                    unsigned c0 = cc.x & 0xffffu, c1 = cc.x >> 16;
                    unsigned c2 = cc.y & 0xffffu, c3 = cc.y >> 16;
                    if ((bits[c0 >> 5] >> (c0 & 31)) & 1u) acc += w.x;
                    if ((bits[c1 >> 5] >> (c1 & 31)) & 1u) acc += w.y;
                    if ((bits[c2 >> 5] >> (c2 & 31)) & 1u) acc += w.z;
                    if ((bits[c3 >> 5] >> (c3 & 31)) & 1u) acc += w.w;
                }
            }
            #pragma unroll
            for (int off = 1; off < 64; off <<= 1) acc += __shfl_xor(acc, off);
            if (lane == 0) {
                float cur = subtractive ? (rowsum[r] - acc) : acc;
                float vn = DECAY * v[r] + cur;
                float f = (vn >= THRESH) ? 1.0f : 0.0f;
                out[(size_t)t * N_NEURONS + r] = f;
                out[(size_t)(T_STEPS + t) * N_NEURONS + r] = vn;
                v[r] = (f > 0.f) ? 0.f : vn;
                if (f > 0.f) atomicOr(&newbits[r >> 5], 1u << (r & 31));
            }
        }
        __syncthreads();
        if (tid < 256) bits[tid] = newbits[tid];
        __syncthreads();
    }
}

// ---- Dense fallback if ws is too small for any compressed format ----
__global__ __launch_bounds__(256) void step_dense(const float* __restrict__ W,
                                                  const float* __restrict__ fin,
                                                  float* __restrict__ fout,
                                                  float* __restrict__ v,
                                                  float* __restrict__ out_fire,
                                                  float* __restrict__ out_v) {
    __shared__ float fs[N_NEURONS];
    const float4* f4 = (const float4*)fin;
    float4* fs4 = (float4*)fs;
    #pragma unroll
    for (int k = 0; k < N_NEURONS / 4 / 256; ++k)
        fs4[k * 256 + threadIdx.x] = f4[k * 256 + threadIdx.x];
    __syncthreads();

    const int wave = threadIdx.x >> 6, lane = threadIdx.x & 63;
    const int row = blockIdx.x * 4 + wave;
    const float4* Wrow = (const float4*)(W + (size_t)row * N_NEURONS);

    float acc = 0.f;
    #pragma unroll 8
    for (int k = 0; k < N_NEURONS / 4 / 64; ++k) {
        const int idx = k * 64 + lane;
        float4 w = Wrow[idx];
        float4 f = fs4[idx];
        acc += w.x * f.x + w.y * f.y + w.z * f.z + w.w * f.w;
    }
    #pragma unroll
    for (int off = 32; off; off >>= 1) acc += __shfl_down(acc, off);

    if (lane == 0) {
        float vn   = DECAY * v[row] + acc;
        float fire = (vn >= THRESH) ? 1.0f : 0.0f;
        out_fire[row] = fire;
        out_v[row]    = vn;
        fout[row]     = fire;
        v[row]        = (fire > 0.f) ? 0.f : vn;
    }
}

extern "C" void kernel_launch(void* const* d_in, const int* in_sizes, int n_in,
                              void* d_out, int out_size, void* d_ws, size_t ws_size,
                              hipStream_t stream) {
    const float* W  = (const float*)d_in[1];
    const float* f0 = (const float*)d_in[2];
    const float* v0 = (const float*)d_in[3];
    float* out = (float*)d_out;

    char* ws = (char*)d_ws;
    float* v   = (float*)(ws + WS_V_OFF);
    float* fb0 = (float*)(ws + WS_FB0_OFF);
    float* fb1 = (float*)(ws + WS_FB1_OFF);
    unsigned short* m0 = (unsigned short*)(ws + WS_M0_OFF);
    unsigned short* m1 = (unsigned short*)(ws + WS_M1_OFF);
    float* rowsum           = (float*)(ws + WS_RSUM_OFF);
    unsigned* row_start     = (unsigned*)(ws + WS_RS_OFF);
    unsigned* row_end       = (unsigned*)(ws + WS_RE_OFF);
    unsigned* rowtot        = (unsigned*)(ws + WS_RT_OFF);
    unsigned short* laneoff = (unsigned short*)(ws + WS_LO_OFF);
    unsigned* done          = (unsigned*)(ws + WS_DONE_OFF);
    int* mrs                = (int*)(ws + WS_MRS_OFF);
    float* val              = (float*)(ws + WS_VAL_OFF);

    const bool ell = (ws_size >= WS_ELL_REQUIRED);
    const bool csr = (ws_size >= WS_CSR_REQUIRED);
    unsigned short* col = (unsigned short*)(ws + (ell ? WS_ELL_COL_OFF : WS_CSR_COL_OFF));

    init_state<<<(N_NEURONS + 255) / 256, 256, 0, stream>>>(
        f0, v0, v, fb0, m0, done, mrs);

    if (ell || csr) {
        if (ell) {
            fill_ell<<<N_NEURONS / 4, 256, 0, stream>>>(
                W, row_start, row_end, val, col, rowsum);
        } else {
            count_rows<<<N_NEURONS / 4, 256, 0, stream>>>(W, rowtot, laneoff);
            scan_rows<<<1, 1024, 0, stream>>>(rowtot, row_start, row_end);
            fill_csr<<<N_NEURONS / 4, 256, 0, stream>>>(
                W, row_start, row_end, rowtot, laneoff, val, col, rowsum);
        }
        reduce_mrs<<<1, 1024, 0, stream>>>(rowsum, mrs);
        unsigned short* masks[2] = {m0, m1};
        for (int t = 0; t < K_STEPS; ++t) {
            step_adaptive<<<SB_BLOCKS, SB_THREADS, 0, stream>>>(
                row_start, row_end, val, col, rowsum, W,
                (const unsigned*)masks[t & 1], masks[(t + 1) & 1],
                v, out, done, mrs, t);
        }
        step_tail<<<1, 1024, 0, stream>>>(
            row_start, row_end, val, col, rowsum, W,
            (const unsigned*)masks[K_STEPS & 1], v, out, done, mrs);
    } else {
        float* fbufs[2] = {fb0, fb1};
        for (int t = 0; t < T_STEPS; ++t) {
            const float* fin = fbufs[t & 1];
            float* fout      = fbufs[(t + 1) & 1];
            step_dense<<<N_NEURONS / 4, 256, 0, stream>>>(
                W, fin, fout, v,
                out + (size_t)t * N_NEURONS,
                out + (size_t)(T_STEPS + t) * N_NEURONS);
        }
    }
}

// Round 11
// 144.622 us; speedup vs baseline: 23.8991x; 1.3207x over previous
//
#include <hip/hip_runtime.h>
#include <hip/hip_bf16.h>

// SpikingLayer: T=64 sequential LIF steps, cur = W @ f, W ~12% dense.
// Round-11: W is read from HBM EXACTLY ONCE.
//   build_step0: fused ELL build + step t=0. Wave per row; each half-row
//     (16 float4) held in registers: count + wave-scan + LDS compaction +
//     f0-masked accumulation (cur for t=0) in one pass. Then vectorized ELL
//     dump, gather-order rowsum, LIF update, fire-bit atomicOr into m1.
//   steps t=1..7: step_adaptive (absorption at t~3-4; 2x margin), then
//     step_tail (1 block) correctly finishes t=8..63 if ever needed.
//   step_adaptive modes (z = #non-firing from mask popcount):
//     z==0 && minrs>=1 : absorbing -> fill ALL remaining outputs, set done
//     z==0             : cur = rowsum
//     0<z<=256         : cur = rowsum - sum_{j nonfiring} W[row][j]
//     else             : full ELL gather
// Output layout (flat): fires[T][N] at 0, vs[T][N] at T*N.

#define N_NEURONS 8192
#define T_STEPS   64
#define DECAY     0.9f
#define THRESH    1.0f
#define ELL_SLOT  1280      // max nnz/row ~1180 (mean ~1030)
#define STAGE_CAP 1280
#define NNZ_CAP   9437184u  // CSR fallback cap
#define ZS_CUT    256
#define K_STEPS   8         // individually-launched steps before the tail

#define SB_BLOCKS  512      // step grid: 16 rows/block, 8 waves, 2 rows/wave
#define SB_THREADS 512

// ws byte layout (shared header for all paths):
#define WS_V_OFF    0         // 8192 f32
#define WS_FB0_OFF  32768     // 8192 f32 (dense fallback)
#define WS_FB1_OFF  65536     // 8192 f32 (dense fallback)
#define WS_M0_OFF   98304     // 1024 B mask (bit n = neuron n firing)
#define WS_M1_OFF   99328     // 1024 B mask
#define WS_RSUM_OFF 100352    // 8192 f32 row sums
#define WS_RS_OFF   133120    // 8192 u32 row_start
#define WS_RE_OFF   165888    // 8192 u32 row_end
#define WS_RT_OFF   198656    // 8192 u32 raw row totals (CSR path)
#define WS_LO_OFF   231424    // u16 laneoff[8192][64] = 1 MB (CSR path)
#define WS_DONE_OFF 1280000   // u32 done flag
#define WS_MRS_OFF  1280128   // i32 min-rowsum bits
#define WS_VAL_OFF  1280256   // values (16B aligned)
#define WS_ELL_COL_OFF (WS_VAL_OFF + (size_t)N_NEURONS * ELL_SLOT * 4)
#define WS_ELL_REQUIRED (WS_ELL_COL_OFF + (size_t)N_NEURONS * ELL_SLOT * 2)
#define WS_CSR_COL_OFF (WS_VAL_OFF + (size_t)NNZ_CAP * 4)
#define WS_CSR_REQUIRED (WS_CSR_COL_OFF + (size_t)NNZ_CAP * 2)

__global__ __launch_bounds__(256) void init_state(const float* __restrict__ f0,
                                                  const float* __restrict__ v0,
                                                  float* __restrict__ v,
                                                  float* __restrict__ fbuf0,
                                                  unsigned short* __restrict__ m0,
                                                  unsigned* __restrict__ m1,
                                                  unsigned* __restrict__ done,
                                                  int* __restrict__ mrs) {
    int i = blockIdx.x * 256 + threadIdx.x;
    if (i < N_NEURONS) {
        v[i] = v0[i];
        fbuf0[i] = f0[i];
    }
    if (i < N_NEURONS / 16) {
        unsigned b = 0;
        #pragma unroll
        for (int j = 0; j < 16; ++j) b |= (f0[i * 16 + j] != 0.f ? 1u : 0u) << j;
        m0[i] = (unsigned short)b;
    }
    if (i < N_NEURONS / 32) m1[i] = 0u;   // pre-zero for build_step0 atomicOr
    if (i == 0) { *done = 0u; *mrs = 0x7F7FFFFF; }  // FLT_MAX
}

// ---- Fused ELL build + step 0: ONE HBM pass over W. ----
__global__ __launch_bounds__(256) void build_step0(
        const float* __restrict__ W, const float* __restrict__ v0,
        const unsigned* __restrict__ m_in,   // f0 mask, u32[256]
        unsigned* __restrict__ m_out,        // step-0 fire mask, pre-zeroed
        unsigned* __restrict__ row_start, unsigned* __restrict__ row_end,
        float* __restrict__ val, unsigned short* __restrict__ col,
        float* __restrict__ rowsum, float* __restrict__ v,
        float* __restrict__ out) {
    __shared__ float          sval[4][STAGE_CAP];
    __shared__ unsigned short scol[4][STAGE_CAP];
    __shared__ unsigned bits[256];

    const int wave = threadIdx.x >> 6, lane = threadIdx.x & 63;
    const int row = blockIdx.x * 4 + wave;
    const float4* Wr = (const float4*)(W + (size_t)row * N_NEURONS);

    if (threadIdx.x < 256) bits[threadIdx.x] = m_in[threadIdx.x];
    __syncthreads();

    float cur = 0.f;       // masked sum for step 0 (per-lane, k-order)
    unsigned base = 0;     // wave-uniform running nnz across halves

    #pragma unroll
    for (int h = 0; h < 2; ++h) {
        // Read half-row into registers (the only HBM read of W).
        float4 w[16];
        #pragma unroll
        for (int k = 0; k < 16; ++k) w[k] = Wr[h * 1024 + k * 64 + lane];

        int c = 0;
        #pragma unroll
        for (int k = 0; k < 16; ++k) {
            const int idx = h * 1024 + k * 64 + lane;     // float4 index
            // one LDS word read covers all 4 flags (idx&7 nibble)
            const unsigned f4b = bits[idx >> 3] >> ((idx & 7) * 4);
            c += (w[k].x != 0.f) + (w[k].y != 0.f) + (w[k].z != 0.f) + (w[k].w != 0.f);
            if ((f4b & 1u) && w[k].x != 0.f) cur += w[k].x;
            if ((f4b & 2u) && w[k].y != 0.f) cur += w[k].y;
            if ((f4b & 4u) && w[k].z != 0.f) cur += w[k].z;
            if ((f4b & 8u) && w[k].w != 0.f) cur += w[k].w;
        }
        int incl = c;
        #pragma unroll
        for (int off = 1; off < 64; off <<= 1) {
            int n = __shfl_up(incl, off);
            if (lane >= off) incl += n;
        }
        unsigned p = base + (unsigned)(incl - c);
        #pragma unroll
        for (int k = 0; k < 16; ++k) {
            const int c0 = (h * 1024 + k * 64 + lane) * 4;
            if (w[k].x != 0.f) { sval[wave][p] = w[k].x; scol[wave][p] = (unsigned short)c0;       ++p; }
            if (w[k].y != 0.f) { sval[wave][p] = w[k].y; scol[wave][p] = (unsigned short)(c0 + 1); ++p; }
            if (w[k].z != 0.f) { sval[wave][p] = w[k].z; scol[wave][p] = (unsigned short)(c0 + 2); ++p; }
            if (w[k].w != 0.f) { sval[wave][p] = w[k].w; scol[wave][p] = (unsigned short)(c0 + 3); ++p; }
        }
        base += (unsigned)__shfl(incl, 63);
    }

    const unsigned total  = base;
    const unsigned padded = (total + 3u) & ~3u;
    const unsigned gbase  = (unsigned)row * ELL_SLOT;
    if (lane == 0) { row_start[row] = gbase; row_end[row] = gbase + padded; }
    if (lane < (int)(padded - total)) {   // zero pads
        sval[wave][total + lane] = 0.f;
        scol[wave][total + lane] = 0;
    }

    // Vectorized ELL dump (each wave owns its LDS row).
    const float4* sv4 = (const float4*)(&sval[wave][0]);
    float4* v4 = (float4*)(val + gbase);
    for (unsigned i = lane; i < padded / 4u; i += 64) v4[i] = sv4[i];
    const uint2* sc4 = (const uint2*)(&scol[wave][0]);
    uint2* c4 = (uint2*)(col + gbase);
    for (unsigned i = lane; i < padded / 4u; i += 64) c4[i] = sc4[i];

    // rowsum in the step kernel's exact gather order (bit-exact for absorb).
    float rsum = 0.f;
    for (unsigned i = (unsigned)lane * 4u; i < padded; i += 256u) {
        rsum += sval[wave][i];
        rsum += sval[wave][i + 1];
        rsum += sval[wave][i + 2];
        rsum += sval[wave][i + 3];
    }
    #pragma unroll
    for (int off = 1; off < 64; off <<= 1) rsum += __shfl_xor(rsum, off);

    // Step 0 LIF update.
    #pragma unroll
    for (int off = 1; off < 64; off <<= 1) cur += __shfl_xor(cur, off);
    if (lane == 0) {
        rowsum[row] = rsum;
        float vn = DECAY * v0[row] + cur;
        float f  = (vn >= THRESH) ? 1.0f : 0.0f;
        out[row] = f;
        out[(size_t)T_STEPS * N_NEURONS + row] = vn;
        v[row] = (f > 0.f) ? 0.f : vn;
        if (f > 0.f) atomicOr(&m_out[row >> 5], 1u << (row & 31));
    }
}

// ---- CSR fallback build (round-9, atomic-free) ----
__global__ __launch_bounds__(256) void count_rows(const float* __restrict__ W,
                                                  unsigned* __restrict__ rowtot,
                                                  unsigned short* __restrict__ laneoff) {
    const int wave = threadIdx.x >> 6, lane = threadIdx.x & 63;
    const int row = blockIdx.x * 4 + wave;
    const float4* Wr = (const float4*)(W + (size_t)row * N_NEURONS);
    int c = 0;
    #pragma unroll 8
    for (int k = 0; k < 32; ++k) {
        float4 w = Wr[k * 64 + lane];
        c += (w.x != 0.f) + (w.y != 0.f) + (w.z != 0.f) + (w.w != 0.f);
    }
    int incl = c;
    #pragma unroll
    for (int off = 1; off < 64; off <<= 1) {
        int n = __shfl_up(incl, off);
        if (lane >= off) incl += n;
    }
    if (lane == 63) rowtot[row] = (unsigned)incl;
    laneoff[(size_t)row * 64 + lane] = (unsigned short)(incl - c);
}

__global__ __launch_bounds__(1024) void scan_rows(const unsigned* __restrict__ rowtot,
                                                  unsigned* __restrict__ row_start,
                                                  unsigned* __restrict__ row_end) {
    __shared__ unsigned part[1024];
    const int t = threadIdx.x;
    unsigned c[8], s = 0;
    #pragma unroll
    for (int i = 0; i < 8; ++i) {
        c[i] = (rowtot[t * 8 + i] + 3u) & ~3u;
        s += c[i];
    }
    part[t] = s;
    __syncthreads();
    for (int off = 1; off < 1024; off <<= 1) {
        unsigned add = (t >= off) ? part[t - off] : 0u;
        __syncthreads();
        part[t] += add;
        __syncthreads();
    }
    unsigned base = part[t] - s;
    #pragma unroll
    for (int i = 0; i < 8; ++i) {
        row_start[t * 8 + i] = base;
        base += c[i];
        row_end[t * 8 + i] = base;
    }
}

__global__ __launch_bounds__(256) void fill_csr(const float* __restrict__ W,
                                                const unsigned* __restrict__ row_start,
                                                const unsigned* __restrict__ row_end,
                                                const unsigned* __restrict__ rowtot,
                                                const unsigned short* __restrict__ laneoff,
                                                float* __restrict__ val,
                                                unsigned short* __restrict__ col,
                                                float* __restrict__ rowsum) {
    __shared__ float          sval[4][STAGE_CAP];
    __shared__ unsigned short scol[4][STAGE_CAP];

    const int wave = threadIdx.x >> 6, lane = threadIdx.x & 63;
    const int row = blockIdx.x * 4 + wave;
    const float4* Wr = (const float4*)(W + (size_t)row * N_NEURONS);

    const unsigned gbase  = row_start[row];
    const unsigned padded = row_end[row] - gbase;
    const unsigned total  = rowtot[row];
    unsigned p = laneoff[(size_t)row * 64 + lane];

    #pragma unroll 4
    for (int k = 0; k < 32; ++k) {
        const int idx = k * 64 + lane;
        float4 w = Wr[idx];
        const int c0 = idx * 4;
        if (w.x != 0.f) { sval[wave][p] = w.x; scol[wave][p] = (unsigned short)c0;       ++p; }
        if (w.y != 0.f) { sval[wave][p] = w.y; scol[wave][p] = (unsigned short)(c0 + 1); ++p; }
        if (w.z != 0.f) { sval[wave][p] = w.z; scol[wave][p] = (unsigned short)(c0 + 2); ++p; }
        if (w.w != 0.f) { sval[wave][p] = w.w; scol[wave][p] = (unsigned short)(c0 + 3); ++p; }
    }
    if (lane < (int)(padded - total)) {
        sval[wave][total + lane] = 0.f;
        scol[wave][total + lane] = 0;
    }

    const float4* sv4 = (const float4*)(&sval[wave][0]);
    float4* v4 = (float4*)(val + gbase);
    for (unsigned i = lane; i < padded / 4u; i += 64) v4[i] = sv4[i];
    const uint2* sc4 = (const uint2*)(&scol[wave][0]);
    uint2* c4 = (uint2*)(col + gbase);
    for (unsigned i = lane; i < padded / 4u; i += 64) c4[i] = sc4[i];

    float rsum = 0.f;
    for (unsigned i = (unsigned)lane * 4u; i < padded; i += 256u) {
        rsum += sval[wave][i];
        rsum += sval[wave][i + 1];
        rsum += sval[wave][i + 2];
        rsum += sval[wave][i + 3];
    }
    #pragma unroll
    for (int off = 1; off < 64; off <<= 1) rsum += __shfl_xor(rsum, off);
    if (lane == 0) rowsum[row] = rsum;
}

__global__ __launch_bounds__(1024) void reduce_mrs(const float* __restrict__ rowsum,
                                                   int* __restrict__ mrs) {
    __shared__ float sm[16];
    const int t = threadIdx.x, wave = t >> 6, lane = t & 63;
    float m = 3.4e38f;
    #pragma unroll
    for (int i = 0; i < 8; ++i) m = fminf(m, rowsum[i * 1024 + t]);
    #pragma unroll
    for (int off = 1; off < 64; off <<= 1) m = fminf(m, __shfl_xor(m, off));
    if (lane == 0) sm[wave] = m;
    __syncthreads();
    if (t == 0) {
        #pragma unroll
        for (int i = 1; i < 16; ++i) m = fminf(m, sm[i]);
        *mrs = __float_as_int(m);
    }
}

// Adaptive step. 512 blocks x 512 threads; block owns 16 rows; wave owns 2.
__global__ __launch_bounds__(SB_THREADS) void step_adaptive(
        const unsigned* __restrict__ row_start, const unsigned* __restrict__ row_end,
        const float* __restrict__ val, const unsigned short* __restrict__ col,
        const float* __restrict__ rowsum, const float* __restrict__ W,
        const unsigned* __restrict__ min_mask, unsigned short* __restrict__ mout,
        float* __restrict__ v, float* __restrict__ out,
        unsigned* __restrict__ done, const int* __restrict__ mrs, int t) {
    if (*done) return;

    __shared__ unsigned bits[N_NEURONS / 32];
    __shared__ float sfire[16];
    __shared__ int kcnt, wpart[4];
    __shared__ unsigned short zlist[ZS_CUT];

    const int tid = threadIdx.x, wave = tid >> 6, lane = tid & 63;
    const int bb = blockIdx.x * 16;
    const int r0 = bb + wave * 2, r1 = r0 + 1;

    if (tid == 0) kcnt = 0;
    __syncthreads();
    if (tid < 256) {
        unsigned w = min_mask[tid];
        bits[tid] = w;
        atomicAdd(&kcnt, __popc(w));
    }
    __syncthreads();
    const int z = N_NEURONS - kcnt;
    const float minrs = __int_as_float(*mrs);

    if (z == 0 && minrs >= THRESH) {
        if (tid < 16) {
            const float rs = rowsum[bb + tid];
            for (int tt = t; tt < T_STEPS; ++tt) {
                out[(size_t)tt * N_NEURONS + bb + tid] = 1.0f;
                out[(size_t)(T_STEPS + tt) * N_NEURONS + bb + tid] = rs;
            }
        }
        __syncthreads();
        if (tid == 0) *done = 1u;
        return;
    }

    float acc0 = 0.f, acc1 = 0.f;
    const bool subtractive = (z <= ZS_CUT);

    if (z > 0 && z <= ZS_CUT) {
        int zc = 0, word = 0, incl = 0;
        if (tid < 256) {
            word = (int)bits[tid];
            zc = 32 - __popc((unsigned)word);
            incl = zc;
            #pragma unroll
            for (int off = 1; off < 64; off <<= 1) {
                int n = __shfl_up(incl, off);
                if (lane >= off) incl += n;
            }
            if (lane == 63) wpart[wave] = incl;
        }
        __syncthreads();
        if (tid < 256) {
            int base = 0;
            for (int wv = 0; wv < wave; ++wv) base += wpart[wv];
            int off = base + incl - zc;
            for (int b = 0; b < 32; ++b)
                if (!((word >> b) & 1)) zlist[off++] = (unsigned short)(tid * 32 + b);
        }
        __syncthreads();
        const float* Wr0 = W + (size_t)r0 * N_NEURONS;
        const float* Wr1 = W + (size_t)r1 * N_NEURONS;
        for (int i = lane; i < z; i += 64) {
            const int j = zlist[i];
            acc0 += Wr0[j];
            acc1 += Wr1[j];
        }
    } else if (z > ZS_CUT) {
        const unsigned s0 = row_start[r0], e0 = row_end[r0];
        for (unsigned k = s0 + (unsigned)lane * 4u; k < e0; k += 256u) {
            float4 w = *(const float4*)(val + k);
            uint2 cc = *(const uint2*)(col + k);
            unsigned c0 = cc.x & 0xffffu, c1 = cc.x >> 16;
            unsigned c2 = cc.y & 0xffffu, c3 = cc.y >> 16;
            if ((bits[c0 >> 5] >> (c0 & 31)) & 1u) acc0 += w.x;
            if ((bits[c1 >> 5] >> (c1 & 31)) & 1u) acc0 += w.y;
            if ((bits[c2 >> 5] >> (c2 & 31)) & 1u) acc0 += w.z;
            if ((bits[c3 >> 5] >> (c3 & 31)) & 1u) acc0 += w.w;
        }
        const unsigned s1 = row_start[r1], e1 = row_end[r1];
        for (unsigned k = s1 + (unsigned)lane * 4u; k < e1; k += 256u) {
            float4 w = *(const float4*)(val + k);
            uint2 cc = *(const uint2*)(col + k);
            unsigned c0 = cc.x & 0xffffu, c1 = cc.x >> 16;
            unsigned c2 = cc.y & 0xffffu, c3 = cc.y >> 16;
            if ((bits[c0 >> 5] >> (c0 & 31)) & 1u) acc1 += w.x;
            if ((bits[c1 >> 5] >> (c1 & 31)) & 1u) acc1 += w.y;
            if ((bits[c2 >> 5] >> (c2 & 31)) & 1u) acc1 += w.z;
            if ((bits[c3 >> 5] >> (c3 & 31)) & 1u) acc1 += w.w;
        }
    }
    #pragma unroll
    for (int off = 1; off < 64; off <<= 1) {
        acc0 += __shfl_xor(acc0, off);
        acc1 += __shfl_xor(acc1, off);
    }

    if (lane == 0) {
        float cur0 = subtractive ? (rowsum[r0] - acc0) : acc0;
        float cur1 = subtractive ? (rowsum[r1] - acc1) : acc1;
        float vn0 = DECAY * v[r0] + cur0;
        float vn1 = DECAY * v[r1] + cur1;
        float f0 = (vn0 >= THRESH) ? 1.0f : 0.0f;
        float f1 = (vn1 >= THRESH) ? 1.0f : 0.0f;
        out[(size_t)t * N_NEURONS + r0] = f0;
        out[(size_t)t * N_NEURONS + r1] = f1;
        out[(size_t)(T_STEPS + t) * N_NEURONS + r0] = vn0;
        out[(size_t)(T_STEPS + t) * N_NEURONS + r1] = vn1;
        v[r0] = (f0 > 0.f) ? 0.f : vn0;
        v[r1] = (f1 > 0.f) ? 0.f : vn1;
        sfire[wave * 2] = f0;
        sfire[wave * 2 + 1] = f1;
    }
    __syncthreads();
    if (tid == 0) {
        unsigned b16 = 0;
        #pragma unroll
        for (int i = 0; i < 16; ++i) b16 |= (sfire[i] > 0.f ? 1u : 0u) << i;
        mout[blockIdx.x] = (unsigned short)b16;
    }
}

// Tail: ONE block finishes steps K_STEPS..63 if absorption hasn't happened.
__global__ __launch_bounds__(1024) void step_tail(
        const unsigned* __restrict__ row_start, const unsigned* __restrict__ row_end,
        const float* __restrict__ val, const unsigned short* __restrict__ col,
        const float* __restrict__ rowsum, const float* __restrict__ W,
        const unsigned* __restrict__ mask_in,
        float* __restrict__ v, float* __restrict__ out,
        const unsigned* __restrict__ done, const int* __restrict__ mrs) {
    if (*done) return;

    __shared__ unsigned bits[256], newbits[256];
    __shared__ int kcnt, wpart[4];
    __shared__ unsigned short zlist[ZS_CUT];

    const int tid = threadIdx.x, wave = tid >> 6, lane = tid & 63;
    const float minrs = __int_as_float(*mrs);

    if (tid < 256) bits[tid] = mask_in[tid];
    __syncthreads();

    for (int t = K_STEPS; t < T_STEPS; ++t) {
        if (tid == 0) kcnt = 0;
        __syncthreads();
        if (tid < 256) atomicAdd(&kcnt, __popc(bits[tid]));
        __syncthreads();
        const int z = N_NEURONS - kcnt;

        if (z == 0 && minrs >= THRESH) {
            for (int tt = t; tt < T_STEPS; ++tt)
                for (int i = tid; i < N_NEURONS; i += 1024) {
                    out[(size_t)tt * N_NEURONS + i] = 1.0f;
                    out[(size_t)(T_STEPS + tt) * N_NEURONS + i] = rowsum[i];
                }
            return;
        }

        const bool subtractive = (z <= ZS_CUT);
        if (z > 0 && z <= ZS_CUT) {
            int zc = 0, word = 0, incl = 0;
            if (tid < 256) {
                word = (int)bits[tid];
                zc = 32 - __popc((unsigned)word);
                incl = zc;
                #pragma unroll
                for (int off = 1; off < 64; off <<= 1) {
                    int n = __shfl_up(incl, off);
                    if (lane >= off) incl += n;
                }
                if (lane == 63) wpart[wave] = incl;
            }
            __syncthreads();
            if (tid < 256) {
                int base = 0;
                for (int wv = 0; wv < wave; ++wv) base += wpart[wv];
                int off = base + incl - zc;
                for (int b = 0; b < 32; ++b)
                    if (!((word >> b) & 1)) zlist[off++] = (unsigned short)(tid * 32 + b);
            }
            __syncthreads();
        }
        if (tid < 256) newbits[tid] = 0;
        __syncthreads();

        for (int r = wave; r < N_NEURONS; r += 16) {
            float acc = 0.f;
            if (z > 0 && z <= ZS_CUT) {
                const float* Wr = W + (size_t)r * N_NEURONS;
                for (int i = lane; i < z; i += 64) acc += Wr[zlist[i]];
            } else if (z > ZS_CUT) {
                const unsigned s = row_start[r], e = row_end[r];
                for (unsigned k = s + (unsigned)lane * 4u; k < e; k += 256u) {
                    float4 w = *(const float4*)(val + k);
                    uint2 cc = *(const uint2*)(col + k);
                    unsigned c0 = cc.x & 0xffffu, c1 = cc.x >> 16;
                    unsigned c2 = cc.y & 0xffffu, c3 = cc.y >> 16;
                    if ((bits[c0 >> 5] >> (c0 & 31)) & 1u) acc += w.x;
                    if ((bits[c1 >> 5] >> (c1 & 31)) & 1u) acc += w.y;
                    if ((bits[c2 >> 5] >> (c2 & 31)) & 1u) acc += w.z;
                    if ((bits[c3 >> 5] >> (c3 & 31)) & 1u) acc += w.w;
                }
            }
            #pragma unroll
            for (int off = 1; off < 64; off <<= 1) acc += __shfl_xor(acc, off);
            if (lane == 0) {
                float cur = subtractive ? (rowsum[r] - acc) : acc;
                float vn = DECAY * v[r] + cur;
                float f = (vn >= THRESH) ? 1.0f : 0.0f;
                out[(size_t)t * N_NEURONS + r] = f;
                out[(size_t)(T_STEPS + t) * N_NEURONS + r] = vn;
                v[r] = (f > 0.f) ? 0.f : vn;
                if (f > 0.f) atomicOr(&newbits[r >> 5], 1u << (r & 31));
            }
        }
        __syncthreads();
        if (tid < 256) bits[tid] = newbits[tid];
        __syncthreads();
    }
}

// ---- Dense fallback if ws is too small for any compressed format ----
__global__ __launch_bounds__(256) void step_dense(const float* __restrict__ W,
                                                  const float* __restrict__ fin,
                                                  float* __restrict__ fout,
                                                  float* __restrict__ v,
                                                  float* __restrict__ out_fire,
                                                  float* __restrict__ out_v) {
    __shared__ float fs[N_NEURONS];
    const float4* f4 = (const float4*)fin;
    float4* fs4 = (float4*)fs;
    #pragma unroll
    for (int k = 0; k < N_NEURONS / 4 / 256; ++k)
        fs4[k * 256 + threadIdx.x] = f4[k * 256 + threadIdx.x];
    __syncthreads();

    const int wave = threadIdx.x >> 6, lane = threadIdx.x & 63;
    const int row = blockIdx.x * 4 + wave;
    const float4* Wrow = (const float4*)(W + (size_t)row * N_NEURONS);

    float acc = 0.f;
    #pragma unroll 8
    for (int k = 0; k < N_NEURONS / 4 / 64; ++k) {
        const int idx = k * 64 + lane;
        float4 w = Wrow[idx];
        float4 f = fs4[idx];
        acc += w.x * f.x + w.y * f.y + w.z * f.z + w.w * f.w;
    }
    #pragma unroll
    for (int off = 32; off; off >>= 1) acc += __shfl_down(acc, off);

    if (lane == 0) {
        float vn   = DECAY * v[row] + acc;
        float fire = (vn >= THRESH) ? 1.0f : 0.0f;
        out_fire[row] = fire;
        out_v[row]    = vn;
        fout[row]     = fire;
        v[row]        = (fire > 0.f) ? 0.f : vn;
    }
}

extern "C" void kernel_launch(void* const* d_in, const int* in_sizes, int n_in,
                              void* d_out, int out_size, void* d_ws, size_t ws_size,
                              hipStream_t stream) {
    const float* W  = (const float*)d_in[1];
    const float* f0 = (const float*)d_in[2];
    const float* v0 = (const float*)d_in[3];
    float* out = (float*)d_out;

    char* ws = (char*)d_ws;
    float* v   = (float*)(ws + WS_V_OFF);
    float* fb0 = (float*)(ws + WS_FB0_OFF);
    float* fb1 = (float*)(ws + WS_FB1_OFF);
    unsigned short* m0 = (unsigned short*)(ws + WS_M0_OFF);
    unsigned short* m1 = (unsigned short*)(ws + WS_M1_OFF);
    float* rowsum           = (float*)(ws + WS_RSUM_OFF);
    unsigned* row_start     = (unsigned*)(ws + WS_RS_OFF);
    unsigned* row_end       = (unsigned*)(ws + WS_RE_OFF);
    unsigned* rowtot        = (unsigned*)(ws + WS_RT_OFF);
    unsigned short* laneoff = (unsigned short*)(ws + WS_LO_OFF);
    unsigned* done          = (unsigned*)(ws + WS_DONE_OFF);
    int* mrs                = (int*)(ws + WS_MRS_OFF);
    float* val              = (float*)(ws + WS_VAL_OFF);

    const bool ell = (ws_size >= WS_ELL_REQUIRED);
    const bool csr = (ws_size >= WS_CSR_REQUIRED);
    unsigned short* col = (unsigned short*)(ws + (ell ? WS_ELL_COL_OFF : WS_CSR_COL_OFF));

    init_state<<<(N_NEURONS + 255) / 256, 256, 0, stream>>>(
        f0, v0, v, fb0, m0, (unsigned*)m1, done, mrs);

    if (ell || csr) {
        unsigned short* masks[2] = {m0, m1};
        int t0 = 0;
        if (ell) {
            // Fused build + step 0: W read from HBM exactly once.
            build_step0<<<N_NEURONS / 4, 256, 0, stream>>>(
                W, v0, (const unsigned*)m0, (unsigned*)m1,
                row_start, row_end, val, col, rowsum, v, out);
            t0 = 1;
        } else {
            count_rows<<<N_NEURONS / 4, 256, 0, stream>>>(W, rowtot, laneoff);
            scan_rows<<<1, 1024, 0, stream>>>(rowtot, row_start, row_end);
            fill_csr<<<N_NEURONS / 4, 256, 0, stream>>>(
                W, row_start, row_end, rowtot, laneoff, val, col, rowsum);
        }
        reduce_mrs<<<1, 1024, 0, stream>>>(rowsum, mrs);
        for (int t = t0; t < K_STEPS; ++t) {
            step_adaptive<<<SB_BLOCKS, SB_THREADS, 0, stream>>>(
                row_start, row_end, val, col, rowsum, W,
                (const unsigned*)masks[t & 1], masks[(t + 1) & 1],
                v, out, done, mrs, t);
        }
        step_tail<<<1, 1024, 0, stream>>>(
            row_start, row_end, val, col, rowsum, W,
            (const unsigned*)masks[K_STEPS & 1], v, out, done, mrs);
    } else {
        float* fbufs[2] = {fb0, fb1};
        for (int t = 0; t < T_STEPS; ++t) {
            const float* fin = fbufs[t & 1];
            float* fout      = fbufs[(t + 1) & 1];
            step_dense<<<N_NEURONS / 4, 256, 0, stream>>>(
                W, fin, fout, v,
                out + (size_t)t * N_NEURONS,
                out + (size_t)(T_STEPS + t) * N_NEURONS);
        }
    }
}

// Round 12
// 138.488 us; speedup vs baseline: 24.9575x; 1.0443x over previous
//
#include <hip/hip_runtime.h>
#include <hip/hip_bf16.h>

// SpikingLayer: T=64 sequential LIF steps, cur = W @ f, W ~12% dense.
// Round-12 (= round-11 minus dead launches):
//   build_step0: fused ELL build + step t=0; W read from HBM EXACTLY ONCE.
//   steps t=1..4: step_adaptive (absorption at t=3 for this input; one wide
//     step of margin), then step_tail (1 block) correctly finishes t=5..63
//     for arbitrary inputs.
//   step_adaptive modes (z = #non-firing from mask popcount):
//     z==0 && minrs>=1 : absorbing -> fill ALL remaining outputs, set done
//     z==0             : cur = rowsum
//     0<z<=256         : cur = rowsum - sum_{j nonfiring} W[row][j]
//     else             : full ELL gather
// Output layout (flat): fires[T][N] at 0, vs[T][N] at T*N.

#define N_NEURONS 8192
#define T_STEPS   64
#define DECAY     0.9f
#define THRESH    1.0f
#define ELL_SLOT  1280      // max nnz/row ~1180 (mean ~1030)
#define STAGE_CAP 1280
#define NNZ_CAP   9437184u  // CSR fallback cap
#define ZS_CUT    256
#define K_STEPS   5         // individually-launched steps before the tail

#define SB_BLOCKS  512      // step grid: 16 rows/block, 8 waves, 2 rows/wave
#define SB_THREADS 512

// ws byte layout (shared header for all paths):
#define WS_V_OFF    0         // 8192 f32
#define WS_FB0_OFF  32768     // 8192 f32 (dense fallback)
#define WS_FB1_OFF  65536     // 8192 f32 (dense fallback)
#define WS_M0_OFF   98304     // 1024 B mask (bit n = neuron n firing)
#define WS_M1_OFF   99328     // 1024 B mask
#define WS_RSUM_OFF 100352    // 8192 f32 row sums
#define WS_RS_OFF   133120    // 8192 u32 row_start
#define WS_RE_OFF   165888    // 8192 u32 row_end
#define WS_RT_OFF   198656    // 8192 u32 raw row totals (CSR path)
#define WS_LO_OFF   231424    // u16 laneoff[8192][64] = 1 MB (CSR path)
#define WS_DONE_OFF 1280000   // u32 done flag
#define WS_MRS_OFF  1280128   // i32 min-rowsum bits
#define WS_VAL_OFF  1280256   // values (16B aligned)
#define WS_ELL_COL_OFF (WS_VAL_OFF + (size_t)N_NEURONS * ELL_SLOT * 4)
#define WS_ELL_REQUIRED (WS_ELL_COL_OFF + (size_t)N_NEURONS * ELL_SLOT * 2)
#define WS_CSR_COL_OFF (WS_VAL_OFF + (size_t)NNZ_CAP * 4)
#define WS_CSR_REQUIRED (WS_CSR_COL_OFF + (size_t)NNZ_CAP * 2)

__global__ __launch_bounds__(256) void init_state(const float* __restrict__ f0,
                                                  const float* __restrict__ v0,
                                                  float* __restrict__ v,
                                                  float* __restrict__ fbuf0,
                                                  unsigned short* __restrict__ m0,
                                                  unsigned* __restrict__ m1,
                                                  unsigned* __restrict__ done,
                                                  int* __restrict__ mrs) {
    int i = blockIdx.x * 256 + threadIdx.x;
    if (i < N_NEURONS) {
        v[i] = v0[i];
        fbuf0[i] = f0[i];
    }
    if (i < N_NEURONS / 16) {
        unsigned b = 0;
        #pragma unroll
        for (int j = 0; j < 16; ++j) b |= (f0[i * 16 + j] != 0.f ? 1u : 0u) << j;
        m0[i] = (unsigned short)b;
    }
    if (i < N_NEURONS / 32) m1[i] = 0u;   // pre-zero for build_step0 atomicOr
    if (i == 0) { *done = 0u; *mrs = 0x7F7FFFFF; }  // FLT_MAX
}

// ---- Fused ELL build + step 0: ONE HBM pass over W. ----
__global__ __launch_bounds__(256) void build_step0(
        const float* __restrict__ W, const float* __restrict__ v0,
        const unsigned* __restrict__ m_in,   // f0 mask, u32[256]
        unsigned* __restrict__ m_out,        // step-0 fire mask, pre-zeroed
        unsigned* __restrict__ row_start, unsigned* __restrict__ row_end,
        float* __restrict__ val, unsigned short* __restrict__ col,
        float* __restrict__ rowsum, float* __restrict__ v,
        float* __restrict__ out) {
    __shared__ float          sval[4][STAGE_CAP];
    __shared__ unsigned short scol[4][STAGE_CAP];
    __shared__ unsigned bits[256];
    __shared__ float sfire[4];

    const int wave = threadIdx.x >> 6, lane = threadIdx.x & 63;
    const int row = blockIdx.x * 4 + wave;
    const float4* Wr = (const float4*)(W + (size_t)row * N_NEURONS);

    if (threadIdx.x < 256) bits[threadIdx.x] = m_in[threadIdx.x];
    __syncthreads();

    float cur = 0.f;       // masked sum for step 0 (per-lane, k-order)
    unsigned base = 0;     // wave-uniform running nnz across halves

    #pragma unroll
    for (int h = 0; h < 2; ++h) {
        // Read half-row into registers (the only HBM read of W).
        float4 w[16];
        #pragma unroll
        for (int k = 0; k < 16; ++k) w[k] = Wr[h * 1024 + k * 64 + lane];

        int c = 0;
        #pragma unroll
        for (int k = 0; k < 16; ++k) {
            const int idx = h * 1024 + k * 64 + lane;     // float4 index
            const unsigned f4b = bits[idx >> 3] >> ((idx & 7) * 4);
            c += (w[k].x != 0.f) + (w[k].y != 0.f) + (w[k].z != 0.f) + (w[k].w != 0.f);
            if ((f4b & 1u) && w[k].x != 0.f) cur += w[k].x;
            if ((f4b & 2u) && w[k].y != 0.f) cur += w[k].y;
            if ((f4b & 4u) && w[k].z != 0.f) cur += w[k].z;
            if ((f4b & 8u) && w[k].w != 0.f) cur += w[k].w;
        }
        int incl = c;
        #pragma unroll
        for (int off = 1; off < 64; off <<= 1) {
            int n = __shfl_up(incl, off);
            if (lane >= off) incl += n;
        }
        unsigned p = base + (unsigned)(incl - c);
        #pragma unroll
        for (int k = 0; k < 16; ++k) {
            const int c0 = (h * 1024 + k * 64 + lane) * 4;
            if (w[k].x != 0.f) { sval[wave][p] = w[k].x; scol[wave][p] = (unsigned short)c0;       ++p; }
            if (w[k].y != 0.f) { sval[wave][p] = w[k].y; scol[wave][p] = (unsigned short)(c0 + 1); ++p; }
            if (w[k].z != 0.f) { sval[wave][p] = w[k].z; scol[wave][p] = (unsigned short)(c0 + 2); ++p; }
            if (w[k].w != 0.f) { sval[wave][p] = w[k].w; scol[wave][p] = (unsigned short)(c0 + 3); ++p; }
        }
        base += (unsigned)__shfl(incl, 63);
    }

    const unsigned total  = base;
    const unsigned padded = (total + 3u) & ~3u;
    const unsigned gbase  = (unsigned)row * ELL_SLOT;
    if (lane == 0) { row_start[row] = gbase; row_end[row] = gbase + padded; }
    if (lane < (int)(padded - total)) {   // zero pads
        sval[wave][total + lane] = 0.f;
        scol[wave][total + lane] = 0;
    }

    // Vectorized ELL dump (each wave owns its LDS row).
    const float4* sv4 = (const float4*)(&sval[wave][0]);
    float4* v4 = (float4*)(val + gbase);
    for (unsigned i = lane; i < padded / 4u; i += 64) v4[i] = sv4[i];
    const uint2* sc4 = (const uint2*)(&scol[wave][0]);
    uint2* c4 = (uint2*)(col + gbase);
    for (unsigned i = lane; i < padded / 4u; i += 64) c4[i] = sc4[i];

    // rowsum in the step kernel's exact gather order (bit-exact for absorb).
    float rsum = 0.f;
    for (unsigned i = (unsigned)lane * 4u; i < padded; i += 256u) {
        rsum += sval[wave][i];
        rsum += sval[wave][i + 1];
        rsum += sval[wave][i + 2];
        rsum += sval[wave][i + 3];
    }
    #pragma unroll
    for (int off = 1; off < 64; off <<= 1) rsum += __shfl_xor(rsum, off);

    // Step 0 LIF update.
    #pragma unroll
    for (int off = 1; off < 64; off <<= 1) cur += __shfl_xor(cur, off);
    if (lane == 0) {
        rowsum[row] = rsum;
        float vn = DECAY * v0[row] + cur;
        float f  = (vn >= THRESH) ? 1.0f : 0.0f;
        out[row] = f;
        out[(size_t)T_STEPS * N_NEURONS + row] = vn;
        v[row] = (f > 0.f) ? 0.f : vn;
        sfire[wave] = f;
    }
    __syncthreads();
    if (threadIdx.x == 0) {
        // One fire-and-forget atomicOr per block (4 rows share a mask word).
        unsigned pat = 0;
        #pragma unroll
        for (int i = 0; i < 4; ++i) pat |= (sfire[i] > 0.f ? 1u : 0u) << i;
        const int rb = blockIdx.x * 4;
        if (pat) atomicOr(&m_out[rb >> 5], pat << (rb & 31));
    }
}

// ---- CSR fallback build (atomic-free) ----
__global__ __launch_bounds__(256) void count_rows(const float* __restrict__ W,
                                                  unsigned* __restrict__ rowtot,
                                                  unsigned short* __restrict__ laneoff) {
    const int wave = threadIdx.x >> 6, lane = threadIdx.x & 63;
    const int row = blockIdx.x * 4 + wave;
    const float4* Wr = (const float4*)(W + (size_t)row * N_NEURONS);
    int c = 0;
    #pragma unroll 8
    for (int k = 0; k < 32; ++k) {
        float4 w = Wr[k * 64 + lane];
        c += (w.x != 0.f) + (w.y != 0.f) + (w.z != 0.f) + (w.w != 0.f);
    }
    int incl = c;
    #pragma unroll
    for (int off = 1; off < 64; off <<= 1) {
        int n = __shfl_up(incl, off);
        if (lane >= off) incl += n;
    }
    if (lane == 63) rowtot[row] = (unsigned)incl;
    laneoff[(size_t)row * 64 + lane] = (unsigned short)(incl - c);
}

__global__ __launch_bounds__(1024) void scan_rows(const unsigned* __restrict__ rowtot,
                                                  unsigned* __restrict__ row_start,
                                                  unsigned* __restrict__ row_end) {
    __shared__ unsigned part[1024];
    const int t = threadIdx.x;
    unsigned c[8], s = 0;
    #pragma unroll
    for (int i = 0; i < 8; ++i) {
        c[i] = (rowtot[t * 8 + i] + 3u) & ~3u;
        s += c[i];
    }
    part[t] = s;
    __syncthreads();
    for (int off = 1; off < 1024; off <<= 1) {
        unsigned add = (t >= off) ? part[t - off] : 0u;
        __syncthreads();
        part[t] += add;
        __syncthreads();
    }
    unsigned base = part[t] - s;
    #pragma unroll
    for (int i = 0; i < 8; ++i) {
        row_start[t * 8 + i] = base;
        base += c[i];
        row_end[t * 8 + i] = base;
    }
}

__global__ __launch_bounds__(256) void fill_csr(const float* __restrict__ W,
                                                const unsigned* __restrict__ row_start,
                                                const unsigned* __restrict__ row_end,
                                                const unsigned* __restrict__ rowtot,
                                                const unsigned short* __restrict__ laneoff,
                                                float* __restrict__ val,
                                                unsigned short* __restrict__ col,
                                                float* __restrict__ rowsum) {
    __shared__ float          sval[4][STAGE_CAP];
    __shared__ unsigned short scol[4][STAGE_CAP];

    const int wave = threadIdx.x >> 6, lane = threadIdx.x & 63;
    const int row = blockIdx.x * 4 + wave;
    const float4* Wr = (const float4*)(W + (size_t)row * N_NEURONS);

    const unsigned gbase  = row_start[row];
    const unsigned padded = row_end[row] - gbase;
    const unsigned total  = rowtot[row];
    unsigned p = laneoff[(size_t)row * 64 + lane];

    #pragma unroll 4
    for (int k = 0; k < 32; ++k) {
        const int idx = k * 64 + lane;
        float4 w = Wr[idx];
        const int c0 = idx * 4;
        if (w.x != 0.f) { sval[wave][p] = w.x; scol[wave][p] = (unsigned short)c0;       ++p; }
        if (w.y != 0.f) { sval[wave][p] = w.y; scol[wave][p] = (unsigned short)(c0 + 1); ++p; }
        if (w.z != 0.f) { sval[wave][p] = w.z; scol[wave][p] = (unsigned short)(c0 + 2); ++p; }
        if (w.w != 0.f) { sval[wave][p] = w.w; scol[wave][p] = (unsigned short)(c0 + 3); ++p; }
    }
    if (lane < (int)(padded - total)) {
        sval[wave][total + lane] = 0.f;
        scol[wave][total + lane] = 0;
    }

    const float4* sv4 = (const float4*)(&sval[wave][0]);
    float4* v4 = (float4*)(val + gbase);
    for (unsigned i = lane; i < padded / 4u; i += 64) v4[i] = sv4[i];
    const uint2* sc4 = (const uint2*)(&scol[wave][0]);
    uint2* c4 = (uint2*)(col + gbase);
    for (unsigned i = lane; i < padded / 4u; i += 64) c4[i] = sc4[i];

    float rsum = 0.f;
    for (unsigned i = (unsigned)lane * 4u; i < padded; i += 256u) {
        rsum += sval[wave][i];
        rsum += sval[wave][i + 1];
        rsum += sval[wave][i + 2];
        rsum += sval[wave][i + 3];
    }
    #pragma unroll
    for (int off = 1; off < 64; off <<= 1) rsum += __shfl_xor(rsum, off);
    if (lane == 0) rowsum[row] = rsum;
}

__global__ __launch_bounds__(1024) void reduce_mrs(const float* __restrict__ rowsum,
                                                   int* __restrict__ mrs) {
    __shared__ float sm[16];
    const int t = threadIdx.x, wave = t >> 6, lane = t & 63;
    float m = 3.4e38f;
    #pragma unroll
    for (int i = 0; i < 8; ++i) m = fminf(m, rowsum[i * 1024 + t]);
    #pragma unroll
    for (int off = 1; off < 64; off <<= 1) m = fminf(m, __shfl_xor(m, off));
    if (lane == 0) sm[wave] = m;
    __syncthreads();
    if (t == 0) {
        #pragma unroll
        for (int i = 1; i < 16; ++i) m = fminf(m, sm[i]);
        *mrs = __float_as_int(m);
    }
}

// Adaptive step. 512 blocks x 512 threads; block owns 16 rows; wave owns 2.
__global__ __launch_bounds__(SB_THREADS) void step_adaptive(
        const unsigned* __restrict__ row_start, const unsigned* __restrict__ row_end,
        const float* __restrict__ val, const unsigned short* __restrict__ col,
        const float* __restrict__ rowsum, const float* __restrict__ W,
        const unsigned* __restrict__ min_mask, unsigned short* __restrict__ mout,
        float* __restrict__ v, float* __restrict__ out,
        unsigned* __restrict__ done, const int* __restrict__ mrs, int t) {
    if (*done) return;

    __shared__ unsigned bits[N_NEURONS / 32];
    __shared__ float sfire[16];
    __shared__ int kcnt, wpart[4];
    __shared__ unsigned short zlist[ZS_CUT];

    const int tid = threadIdx.x, wave = tid >> 6, lane = tid & 63;
    const int bb = blockIdx.x * 16;
    const int r0 = bb + wave * 2, r1 = r0 + 1;

    if (tid == 0) kcnt = 0;
    __syncthreads();
    if (tid < 256) {
        unsigned w = min_mask[tid];
        bits[tid] = w;
        atomicAdd(&kcnt, __popc(w));
    }
    __syncthreads();
    const int z = N_NEURONS - kcnt;
    const float minrs = __int_as_float(*mrs);

    if (z == 0 && minrs >= THRESH) {
        if (tid < 16) {
            const float rs = rowsum[bb + tid];
            for (int tt = t; tt < T_STEPS; ++tt) {
                out[(size_t)tt * N_NEURONS + bb + tid] = 1.0f;
                out[(size_t)(T_STEPS + tt) * N_NEURONS + bb + tid] = rs;
            }
        }
        __syncthreads();
        if (tid == 0) *done = 1u;
        return;
    }

    float acc0 = 0.f, acc1 = 0.f;
    const bool subtractive = (z <= ZS_CUT);

    if (z > 0 && z <= ZS_CUT) {
        int zc = 0, word = 0, incl = 0;
        if (tid < 256) {
            word = (int)bits[tid];
            zc = 32 - __popc((unsigned)word);
            incl = zc;
            #pragma unroll
            for (int off = 1; off < 64; off <<= 1) {
                int n = __shfl_up(incl, off);
                if (lane >= off) incl += n;
            }
            if (lane == 63) wpart[wave] = incl;
        }
        __syncthreads();
        if (tid < 256) {
            int base = 0;
            for (int wv = 0; wv < wave; ++wv) base += wpart[wv];
            int off = base + incl - zc;
            for (int b = 0; b < 32; ++b)
                if (!((word >> b) & 1)) zlist[off++] = (unsigned short)(tid * 32 + b);
        }
        __syncthreads();
        const float* Wr0 = W + (size_t)r0 * N_NEURONS;
        const float* Wr1 = W + (size_t)r1 * N_NEURONS;
        for (int i = lane; i < z; i += 64) {
            const int j = zlist[i];
            acc0 += Wr0[j];
            acc1 += Wr1[j];
        }
    } else if (z > ZS_CUT) {
        const unsigned s0 = row_start[r0], e0 = row_end[r0];
        for (unsigned k = s0 + (unsigned)lane * 4u; k < e0; k += 256u) {
            float4 w = *(const float4*)(val + k);
            uint2 cc = *(const uint2*)(col + k);
            unsigned c0 = cc.x & 0xffffu, c1 = cc.x >> 16;
            unsigned c2 = cc.y & 0xffffu, c3 = cc.y >> 16;
            if ((bits[c0 >> 5] >> (c0 & 31)) & 1u) acc0 += w.x;
            if ((bits[c1 >> 5] >> (c1 & 31)) & 1u) acc0 += w.y;
            if ((bits[c2 >> 5] >> (c2 & 31)) & 1u) acc0 += w.z;
            if ((bits[c3 >> 5] >> (c3 & 31)) & 1u) acc0 += w.w;
        }
        const unsigned s1 = row_start[r1], e1 = row_end[r1];
        for (unsigned k = s1 + (unsigned)lane * 4u; k < e1; k += 256u) {
            float4 w = *(const float4*)(val + k);
            uint2 cc = *(const uint2*)(col + k);
            unsigned c0 = cc.x & 0xffffu, c1 = cc.x >> 16;
            unsigned c2 = cc.y & 0xffffu, c3 = cc.y >> 16;
            if ((bits[c0 >> 5] >> (c0 & 31)) & 1u) acc1 += w.x;
            if ((bits[c1 >> 5] >> (c1 & 31)) & 1u) acc1 += w.y;
            if ((bits[c2 >> 5] >> (c2 & 31)) & 1u) acc1 += w.z;
            if ((bits[c3 >> 5] >> (c3 & 31)) & 1u) acc1 += w.w;
        }
    }
    #pragma unroll
    for (int off = 1; off < 64; off <<= 1) {
        acc0 += __shfl_xor(acc0, off);
        acc1 += __shfl_xor(acc1, off);
    }

    if (lane == 0) {
        float cur0 = subtractive ? (rowsum[r0] - acc0) : acc0;
        float cur1 = subtractive ? (rowsum[r1] - acc1) : acc1;
        float vn0 = DECAY * v[r0] + cur0;
        float vn1 = DECAY * v[r1] + cur1;
        float f0 = (vn0 >= THRESH) ? 1.0f : 0.0f;
        float f1 = (vn1 >= THRESH) ? 1.0f : 0.0f;
        out[(size_t)t * N_NEURONS + r0] = f0;
        out[(size_t)t * N_NEURONS + r1] = f1;
        out[(size_t)(T_STEPS + t) * N_NEURONS + r0] = vn0;
        out[(size_t)(T_STEPS + t) * N_NEURONS + r1] = vn1;
        v[r0] = (f0 > 0.f) ? 0.f : vn0;
        v[r1] = (f1 > 0.f) ? 0.f : vn1;
        sfire[wave * 2] = f0;
        sfire[wave * 2 + 1] = f1;
    }
    __syncthreads();
    if (tid == 0) {
        unsigned b16 = 0;
        #pragma unroll
        for (int i = 0; i < 16; ++i) b16 |= (sfire[i] > 0.f ? 1u : 0u) << i;
        mout[blockIdx.x] = (unsigned short)b16;
    }
}

// Tail: ONE block finishes steps K_STEPS..63 if absorption hasn't happened.
__global__ __launch_bounds__(1024) void step_tail(
        const unsigned* __restrict__ row_start, const unsigned* __restrict__ row_end,
        const float* __restrict__ val, const unsigned short* __restrict__ col,
        const float* __restrict__ rowsum, const float* __restrict__ W,
        const unsigned* __restrict__ mask_in,
        float* __restrict__ v, float* __restrict__ out,
        const unsigned* __restrict__ done, const int* __restrict__ mrs) {
    if (*done) return;

    __shared__ unsigned bits[256], newbits[256];
    __shared__ int kcnt, wpart[4];
    __shared__ unsigned short zlist[ZS_CUT];

    const int tid = threadIdx.x, wave = tid >> 6, lane = tid & 63;
    const float minrs = __int_as_float(*mrs);

    if (tid < 256) bits[tid] = mask_in[tid];
    __syncthreads();

    for (int t = K_STEPS; t < T_STEPS; ++t) {
        if (tid == 0) kcnt = 0;
        __syncthreads();
        if (tid < 256) atomicAdd(&kcnt, __popc(bits[tid]));
        __syncthreads();
        const int z = N_NEURONS - kcnt;

        if (z == 0 && minrs >= THRESH) {
            for (int tt = t; tt < T_STEPS; ++tt)
                for (int i = tid; i < N_NEURONS; i += 1024) {
                    out[(size_t)tt * N_NEURONS + i] = 1.0f;
                    out[(size_t)(T_STEPS + tt) * N_NEURONS + i] = rowsum[i];
                }
            return;
        }

        const bool subtractive = (z <= ZS_CUT);
        if (z > 0 && z <= ZS_CUT) {
            int zc = 0, word = 0, incl = 0;
            if (tid < 256) {
                word = (int)bits[tid];
                zc = 32 - __popc((unsigned)word);
                incl = zc;
                #pragma unroll
                for (int off = 1; off < 64; off <<= 1) {
                    int n = __shfl_up(incl, off);
                    if (lane >= off) incl += n;
                }
                if (lane == 63) wpart[wave] = incl;
            }
            __syncthreads();
            if (tid < 256) {
                int base = 0;
                for (int wv = 0; wv < wave; ++wv) base += wpart[wv];
                int off = base + incl - zc;
                for (int b = 0; b < 32; ++b)
                    if (!((word >> b) & 1)) zlist[off++] = (unsigned short)(tid * 32 + b);
            }
            __syncthreads();
        }
        if (tid < 256) newbits[tid] = 0;
        __syncthreads();

        for (int r = wave; r < N_NEURONS; r += 16) {
            float acc = 0.f;
            if (z > 0 && z <= ZS_CUT) {
                const float* Wr = W + (size_t)r * N_NEURONS;
                for (int i = lane; i < z; i += 64) acc += Wr[zlist[i]];
            } else if (z > ZS_CUT) {
                const unsigned s = row_start[r], e = row_end[r];
                for (unsigned k = s + (unsigned)lane * 4u; k < e; k += 256u) {
                    float4 w = *(const float4*)(val + k);
                    uint2 cc = *(const uint2*)(col + k);
                    unsigned c0 = cc.x & 0xffffu, c1 = cc.x >> 16;
                    unsigned c2 = cc.y & 0xffffu, c3 = cc.y >> 16;
                    if ((bits[c0 >> 5] >> (c0 & 31)) & 1u) acc += w.x;
                    if ((bits[c1 >> 5] >> (c1 & 31)) & 1u) acc += w.y;
                    if ((bits[c2 >> 5] >> (c2 & 31)) & 1u) acc += w.z;
                    if ((bits[c3 >> 5] >> (c3 & 31)) & 1u) acc += w.w;
                }
            }
            #pragma unroll
            for (int off = 1; off < 64; off <<= 1) acc += __shfl_xor(acc, off);
            if (lane == 0) {
                float cur = subtractive ? (rowsum[r] - acc) : acc;
                float vn = DECAY * v[r] + cur;
                float f = (vn >= THRESH) ? 1.0f : 0.0f;
                out[(size_t)t * N_NEURONS + r] = f;
                out[(size_t)(T_STEPS + t) * N_NEURONS + r] = vn;
                v[r] = (f > 0.f) ? 0.f : vn;
                if (f > 0.f) atomicOr(&newbits[r >> 5], 1u << (r & 31));
            }
        }
        __syncthreads();
        if (tid < 256) bits[tid] = newbits[tid];
        __syncthreads();
    }
}

// ---- Dense fallback if ws is too small for any compressed format ----
__global__ __launch_bounds__(256) void step_dense(const float* __restrict__ W,
                                                  const float* __restrict__ fin,
                                                  float* __restrict__ fout,
                                                  float* __restrict__ v,
                                                  float* __restrict__ out_fire,
                                                  float* __restrict__ out_v) {
    __shared__ float fs[N_NEURONS];
    const float4* f4 = (const float4*)fin;
    float4* fs4 = (float4*)fs;
    #pragma unroll
    for (int k = 0; k < N_NEURONS / 4 / 256; ++k)
        fs4[k * 256 + threadIdx.x] = f4[k * 256 + threadIdx.x];
    __syncthreads();

    const int wave = threadIdx.x >> 6, lane = threadIdx.x & 63;
    const int row = blockIdx.x * 4 + wave;
    const float4* Wrow = (const float4*)(W + (size_t)row * N_NEURONS);

    float acc = 0.f;
    #pragma unroll 8
    for (int k = 0; k < N_NEURONS / 4 / 64; ++k) {
        const int idx = k * 64 + lane;
        float4 w = Wrow[idx];
        float4 f = fs4[idx];
        acc += w.x * f.x + w.y * f.y + w.z * f.z + w.w * f.w;
    }
    #pragma unroll
    for (int off = 32; off; off >>= 1) acc += __shfl_down(acc, off);

    if (lane == 0) {
        float vn   = DECAY * v[row] + acc;
        float fire = (vn >= THRESH) ? 1.0f : 0.0f;
        out_fire[row] = fire;
        out_v[row]    = vn;
        fout[row]     = fire;
        v[row]        = (fire > 0.f) ? 0.f : vn;
    }
}

extern "C" void kernel_launch(void* const* d_in, const int* in_sizes, int n_in,
                              void* d_out, int out_size, void* d_ws, size_t ws_size,
                              hipStream_t stream) {
    const float* W  = (const float*)d_in[1];
    const float* f0 = (const float*)d_in[2];
    const float* v0 = (const float*)d_in[3];
    float* out = (float*)d_out;

    char* ws = (char*)d_ws;
    float* v   = (float*)(ws + WS_V_OFF);
    float* fb0 = (float*)(ws + WS_FB0_OFF);
    float* fb1 = (float*)(ws + WS_FB1_OFF);
    unsigned short* m0 = (unsigned short*)(ws + WS_M0_OFF);
    unsigned short* m1 = (unsigned short*)(ws + WS_M1_OFF);
    float* rowsum           = (float*)(ws + WS_RSUM_OFF);
    unsigned* row_start     = (unsigned*)(ws + WS_RS_OFF);
    unsigned* row_end       = (unsigned*)(ws + WS_RE_OFF);
    unsigned* rowtot        = (unsigned*)(ws + WS_RT_OFF);
    unsigned short* laneoff = (unsigned short*)(ws + WS_LO_OFF);
    unsigned* done          = (unsigned*)(ws + WS_DONE_OFF);
    int* mrs                = (int*)(ws + WS_MRS_OFF);
    float* val              = (float*)(ws + WS_VAL_OFF);

    const bool ell = (ws_size >= WS_ELL_REQUIRED);
    const bool csr = (ws_size >= WS_CSR_REQUIRED);
    unsigned short* col = (unsigned short*)(ws + (ell ? WS_ELL_COL_OFF : WS_CSR_COL_OFF));

    init_state<<<(N_NEURONS + 255) / 256, 256, 0, stream>>>(
        f0, v0, v, fb0, m0, (unsigned*)m1, done, mrs);

    if (ell || csr) {
        unsigned short* masks[2] = {m0, m1};
        int t0 = 0;
        if (ell) {
            // Fused build + step 0: W read from HBM exactly once.
            build_step0<<<N_NEURONS / 4, 256, 0, stream>>>(
                W, v0, (const unsigned*)m0, (unsigned*)m1,
                row_start, row_end, val, col, rowsum, v, out);
            t0 = 1;
        } else {
            count_rows<<<N_NEURONS / 4, 256, 0, stream>>>(W, rowtot, laneoff);
            scan_rows<<<1, 1024, 0, stream>>>(rowtot, row_start, row_end);
            fill_csr<<<N_NEURONS / 4, 256, 0, stream>>>(
                W, row_start, row_end, rowtot, laneoff, val, col, rowsum);
        }
        reduce_mrs<<<1, 1024, 0, stream>>>(rowsum, mrs);
        for (int t = t0; t < K_STEPS; ++t) {
            step_adaptive<<<SB_BLOCKS, SB_THREADS, 0, stream>>>(
                row_start, row_end, val, col, rowsum, W,
                (const unsigned*)masks[t & 1], masks[(t + 1) & 1],
                v, out, done, mrs, t);
        }
        step_tail<<<1, 1024, 0, stream>>>(
            row_start, row_end, val, col, rowsum, W,
            (const unsigned*)masks[K_STEPS & 1], v, out, done, mrs);
    } else {
        float* fbufs[2] = {fb0, fb1};
        for (int t = 0; t < T_STEPS; ++t) {
            const float* fin = fbufs[t & 1];
            float* fout      = fbufs[(t + 1) & 1];
            step_dense<<<N_NEURONS / 4, 256, 0, stream>>>(
                W, fin, fout, v,
                out + (size_t)t * N_NEURONS,
                out + (size_t)(T_STEPS + t) * N_NEURONS);
        }
    }
}